// Round 3
// baseline (404.589 us; speedup 1.0000x reference)
//
#include <hip/hip_runtime.h>
#include <cstdint>
#include <cstddef>

// ---------------------------------------------------------------------------
// GatedLatticeLayer on MI355X.  B=16 S=512 W=5 H=512 E=256 V=100000.
// MROWS = B*S = 8192.
//
// Round-3 restructuring: q/hk never materialized.
//   Mt[j,k]  = sum_c Wh[j,512+c] * Wh[k,c]          (512x512, split-bf16 pair)
//   s0[m]    = sum_j (X@Mt^T + u)[m,j] * X[m,j] + cb   (== q . hk, fp32)
//                (rowdot folded into GEMM epilogue, atomicAdd into s0)
//   Wcomb[n,k] = sum_c WkT[n,c] * Wh[k,c]           (896x512 bf16)
//   P        = X @ Wcomb^T + bcomb                  (8192x896 bf16)
//   HV       = X @ WhvT^T + bh[1024:]               (8192x512 fp32)
//   attn: lattice score(t,w) = g_t*(P_t.emb[idx]+qb_t); out = w0*hv
//         + sum alpha_t*bv_t; Ebar (bf16) accumulated -> out += Ebar @ WvT^T
// ---------------------------------------------------------------------------

typedef unsigned short u16;
typedef __attribute__((ext_vector_type(8))) short short8;
typedef __attribute__((ext_vector_type(8))) __bf16 bf16x8;
typedef __attribute__((ext_vector_type(4))) float f32x4;

#define MROWS 8192
#define SS 512

static __device__ __forceinline__ u16 f2bf(float x) {
  uint32_t u = __builtin_bit_cast(uint32_t, x);
  u += 0x7FFFu + ((u >> 16) & 1u);
  return (u16)(u >> 16);
}
static __device__ __forceinline__ float bf2f(u16 h) {
  return __builtin_bit_cast(float, (uint32_t)h << 16);
}
static __device__ __forceinline__ float sigm(float x) { return 1.f / (1.f + __expf(-x)); }

static __device__ __forceinline__ void gl2lds(const u16* g, u16* l) {
  __builtin_amdgcn_global_load_lds(
      (const __attribute__((address_space(1))) unsigned int*)g,
      (__attribute__((address_space(3))) unsigned int*)l, 16, 0, 0);
}

// ---------------- prep: X -> hi/lo bf16  +  lmr  +  s0 zero -----------------
__global__ __launch_bounds__(256) void prep_xlmr(
    const float* __restrict__ X, const float* __restrict__ Wg,
    const float* __restrict__ bg, u16* __restrict__ hi, u16* __restrict__ lo,
    float* __restrict__ lmr, float* __restrict__ s0) {
  __shared__ float wg[4608];
  const int t = threadIdx.x;
  if (blockIdx.x < 32) s0[blockIdx.x * 256 + t] = 0.f;
  for (int i = t; i < 4608; i += 256) wg[i] = Wg[i];
  __syncthreads();
  const int lane = t & 63, wid = t >> 6;
#pragma unroll
  for (int it = 0; it < 4; it++) {
    int pos = blockIdx.x * 16 + it * 4 + wid;
    const float* x = X + (size_t)pos * 512 + lane * 8;
    float4 x0 = *(const float4*)x;
    float4 x1 = *(const float4*)(x + 4);
    float xs[8] = {x0.x, x0.y, x0.z, x0.w, x1.x, x1.y, x1.z, x1.w};
    ushort4 h0, h1, l0, l1;
    h0.x = f2bf(xs[0]); l0.x = f2bf(xs[0] - bf2f(h0.x));
    h0.y = f2bf(xs[1]); l0.y = f2bf(xs[1] - bf2f(h0.y));
    h0.z = f2bf(xs[2]); l0.z = f2bf(xs[2] - bf2f(h0.z));
    h0.w = f2bf(xs[3]); l0.w = f2bf(xs[3] - bf2f(h0.w));
    h1.x = f2bf(xs[4]); l1.x = f2bf(xs[4] - bf2f(h1.x));
    h1.y = f2bf(xs[5]); l1.y = f2bf(xs[5] - bf2f(h1.y));
    h1.z = f2bf(xs[6]); l1.z = f2bf(xs[6] - bf2f(h1.z));
    h1.w = f2bf(xs[7]); l1.w = f2bf(xs[7] - bf2f(h1.w));
    ((ushort4*)hi)[pos * 128 + lane * 2] = h0;
    ((ushort4*)hi)[pos * 128 + lane * 2 + 1] = h1;
    ((ushort4*)lo)[pos * 128 + lane * 2] = l0;
    ((ushort4*)lo)[pos * 128 + lane * 2 + 1] = l1;
    float p[9];
#pragma unroll
    for (int c = 0; c < 9; c++) p[c] = 0.f;
    const float* wrow = wg + (lane * 8) * 9;
#pragma unroll
    for (int j = 0; j < 8; j++)
#pragma unroll
      for (int c = 0; c < 9; c++) p[c] += xs[j] * wrow[j * 9 + c];
#pragma unroll
    for (int c = 0; c < 9; c++)
#pragma unroll
      for (int o = 32; o > 0; o >>= 1) p[c] += __shfl_xor(p[c], o);
    if (lane == 0) {
#pragma unroll
      for (int c = 0; c < 9; c++) lmr[(size_t)pos * 9 + c] = p[c] + bg[c];
    }
  }
}

// ---------------- merged weight preps + gates + bias dots -------------------
// [0,64):   WhvT (Wcat rows 0..511) = transpose of Wh[:,1024:1536], bf16 hi
// [64,128): Whq/Whk split copies (512x512 hi/lo each)
// [128,576): WkT (896x512 bf16)
// [576,672): WvT (512x768 bf16)
// [672,704): gates (8192x3)
// [704,712): bias dots: bcat (1408), u (512), cb (1)
__global__ __launch_bounds__(256) void prep_weights(
    const float* __restrict__ Wh, const float* __restrict__ Wb,
    const float* __restrict__ Wm, const float* __restrict__ We,
    const float* __restrict__ bb, const float* __restrict__ bm,
    const float* __restrict__ be, const float* __restrict__ bh,
    const float* __restrict__ lmr, const int* __restrict__ masks,
    u16* __restrict__ Wcat, u16* __restrict__ Whq_h, u16* __restrict__ Whq_l,
    u16* __restrict__ Whk_h, u16* __restrict__ Whk_l, u16* __restrict__ WkT,
    u16* __restrict__ WvT, float* __restrict__ gates, float* __restrict__ bcat,
    float* __restrict__ u, float* __restrict__ cbuf) {
  __shared__ float tile[64][65];
  const int b = blockIdx.x;
  const int t = threadIdx.x;
  if (b < 64) {
    int k0 = (b & 7) * 64;
    int n0 = (b >> 3) * 64;
#pragma unroll
    for (int i = 0; i < 16; i++) {
      int li = i * 256 + t; int r = li >> 6, c = li & 63;
      tile[r][c] = Wh[(size_t)(k0 + r) * 1536 + 1024 + n0 + c];
    }
    __syncthreads();
#pragma unroll
    for (int i = 0; i < 16; i++) {
      int li = i * 256 + t; int r = li >> 6, c = li & 63;
      Wcat[(size_t)(n0 + r) * 512 + k0 + c] = f2bf(tile[c][r]);
    }
  } else if (b < 128) {
#pragma unroll
    for (int i = 0; i < 4; i++) {
      int q4 = (b - 64) * 1024 + t * 4 + i;   // [0, 65536) float4 index
      int k = q4 >> 7;
      int c4 = (q4 & 127) * 4;
      float4 vq = *(const float4*)(Wh + (size_t)k * 1536 + c4);
      float4 vk = *(const float4*)(Wh + (size_t)k * 1536 + 512 + c4);
      ushort4 qh, ql, kh, kl;
      qh.x = f2bf(vq.x); ql.x = f2bf(vq.x - bf2f(qh.x));
      qh.y = f2bf(vq.y); ql.y = f2bf(vq.y - bf2f(qh.y));
      qh.z = f2bf(vq.z); ql.z = f2bf(vq.z - bf2f(qh.z));
      qh.w = f2bf(vq.w); ql.w = f2bf(vq.w - bf2f(qh.w));
      kh.x = f2bf(vk.x); kl.x = f2bf(vk.x - bf2f(kh.x));
      kh.y = f2bf(vk.y); kl.y = f2bf(vk.y - bf2f(kh.y));
      kh.z = f2bf(vk.z); kl.z = f2bf(vk.z - bf2f(kh.z));
      kh.w = f2bf(vk.w); kl.w = f2bf(vk.w - bf2f(kh.w));
      size_t o = (size_t)k * 512 + c4;
      *(ushort4*)(Whq_h + o) = qh;
      *(ushort4*)(Whq_l + o) = ql;
      *(ushort4*)(Whk_h + o) = kh;
      *(ushort4*)(Whk_l + o) = kl;
    }
  } else if (b < 576) {
    int tid = (b - 128) * 256 + t;      // [0, 896*128)
    int n = tid >> 7;
    int kq = (tid & 127) * 4;
    float4 v;
    if (n < 768) {
      int ty = n >> 8, c = n & 255;
      const float* src = (ty == 0 ? Wb : ty == 1 ? Wm : We) + (size_t)c * 1024 + kq;
      v = *(const float4*)src;
    } else if (n < 771) {
      int ty = n - 768;
      const float* src = (ty == 0 ? bb : ty == 1 ? bm : be) + kq;
      v = *(const float4*)src;
    } else {
      v = make_float4(0.f, 0.f, 0.f, 0.f);
    }
    ushort4 h; h.x = f2bf(v.x); h.y = f2bf(v.y); h.z = f2bf(v.z); h.w = f2bf(v.w);
    ((ushort4*)WkT)[tid] = h;
  } else if (b < 672) {
    int idx = b - 576;                  // [0,96)
    int ty = idx >> 5;
    int rem = idx & 31;
    int c0 = (rem & 3) * 64;
    int n0 = (rem >> 2) * 64;
    const float* Wsrc = ty == 0 ? Wb : ty == 1 ? Wm : We;
#pragma unroll
    for (int i = 0; i < 16; i++) {
      int li = i * 256 + t; int r = li >> 6, c = li & 63;
      tile[r][c] = Wsrc[(size_t)(c0 + r) * 1024 + 512 + n0 + c];
    }
    __syncthreads();
#pragma unroll
    for (int i = 0; i < 16; i++) {
      int li = i * 256 + t; int r = li >> 6, c = li & 63;
      WvT[(size_t)(n0 + r) * 768 + ty * 256 + c0 + c] = f2bf(tile[c][r]);
    }
  } else if (b < 704) {
    int pos = (b - 672) * 256 + t;      // [0,8192)
    int s = pos & (SS - 1);
    float g0, g1, g2;
    if (masks[pos] == 0) {
      g0 = g1 = g2 = 0.f;
    } else if (s == 0 || s == SS - 1) {
      g0 = 1.f; g1 = 0.f; g2 = 1.f;
    } else {
      const float* p0 = lmr + (size_t)(pos - 1) * 9;
      const float* p1 = lmr + (size_t)pos * 9;
      const float* p2 = lmr + (size_t)(pos + 1) * 9;
      g0 = sigm(p0[0] + p1[3] + p2[6]);
      g1 = sigm(p0[1] + p1[4] + p2[7]);
      g2 = sigm(p0[2] + p1[5] + p2[8]);
    }
    gates[(size_t)pos * 3 + 0] = g0;
    gates[(size_t)pos * 3 + 1] = g1;
    gates[(size_t)pos * 3 + 2] = g2;
  } else {
    int tid = (b - 704) * 256 + t;      // [0,2048)
    if (tid < 896) {
      // bcat[512+n] = bcomb[n] = sum_c bh_q[c] * WkT_f32[n,c]
      int n = tid;
      float acc = 0.f;
      if (n < 768) {
        int ty = n >> 8, ce = n & 255;
        const float* src = (ty == 0 ? Wb : ty == 1 ? Wm : We) + (size_t)ce * 1024;
        for (int c = 0; c < 512; c++) acc += bh[c] * src[c];
      } else if (n < 771) {
        int ty = n - 768;
        const float* src = (ty == 0 ? bb : ty == 1 ? bm : be);
        for (int c = 0; c < 512; c++) acc += bh[c] * src[c];
      }
      bcat[512 + n] = acc;
    } else if (tid < 1408) {
      bcat[tid - 896] = bh[1024 + (tid - 896)];   // hv bias
    } else if (tid < 1920) {
      int k = tid - 1408;
      const float* wr = Wh + (size_t)k * 1536;
      float acc = 0.f;
      for (int c = 0; c < 512; c++) acc += wr[c] * bh[512 + c] + wr[512 + c] * bh[c];
      u[k] = acc;
    } else if (tid == 1920) {
      float acc = 0.f;
      for (int c = 0; c < 512; c++) acc += bh[c] * bh[512 + c];
      cbuf[0] = acc;
    }
  }
}

// ---------------- unified MFMA GEMM ----------------------------------------
// C-tile 128x128, 4 waves (2x2), each 4x4 of 16x16x32 bf16 MFMA.
// A(m,K) k-contig; Bt(n,K) k-contig.
// MODE 0: plain, dual out: col<512 -> Cf(HV, ld512)+bias; else Cb(Pb, ld896)+bias
// MODE 1: plain, bf16 out Cb (ldC), no bias
// MODE 2: 3-term split, split-bf16 out (Cb hi, Cb2 lo), ldC, no bias
// MODE 3: 3-term split, bias, no C write; s0[row] += sum_col (v * Xf[row,col])
// MODE 4: plain, fp32 accumulate into Cf (ldC), no bias
template <int MODE>
__global__ __launch_bounds__(256) void gemm_k(
    const u16* __restrict__ Ahi, const u16* __restrict__ Alo,
    const u16* __restrict__ Bhi, const u16* __restrict__ Blo,
    const float* __restrict__ bias, float* __restrict__ Cf,
    u16* __restrict__ Cb, u16* __restrict__ Cb2, int Kdim, int ldC,
    const float* __restrict__ Xf, float* __restrict__ s0) {
  constexpr bool SPLIT = (MODE == 2 || MODE == 3);
  __shared__ __align__(16) u16 As_hi[128 * 32];
  __shared__ __align__(16) u16 Bs_hi[128 * 32];
  __shared__ __align__(16) u16 As_lo[SPLIT ? 128 * 32 : 8];
  __shared__ __align__(16) u16 Bs_lo[SPLIT ? 128 * 32 : 8];

  const int t = threadIdx.x;
  const int lane = t & 63;
  const int wid = t >> 6;
  const int m0 = blockIdx.x * 128;
  const int n0 = blockIdx.y * 128;
  const int wm = (wid & 1) * 64;
  const int wn = (wid >> 1) * 64;
  const int fr = lane & 15;
  const int kq = (lane >> 4) * 8;

  f32x4 acc[4][4];
#pragma unroll
  for (int i = 0; i < 4; i++)
#pragma unroll
    for (int j = 0; j < 4; j++) acc[i][j] = (f32x4){0.f, 0.f, 0.f, 0.f};

  for (int k0 = 0; k0 < Kdim; k0 += 32) {
    __syncthreads();
#pragma unroll
    for (int p = 0; p < 2; p++) {
      int li = p * 256 + t;
      int row = li >> 2;
      int so = (li & 3) * 8;
      size_t ga = (size_t)(m0 + row) * Kdim + k0 + so;
      size_t gb = (size_t)(n0 + row) * Kdim + k0 + so;
      int ls = li * 8;
      gl2lds(&Ahi[ga], &As_hi[ls]);
      gl2lds(&Bhi[gb], &Bs_hi[ls]);
      if constexpr (SPLIT) {
        gl2lds(&Alo[ga], &As_lo[ls]);
        gl2lds(&Blo[gb], &Bs_lo[ls]);
      }
    }
    __syncthreads();
    short8 ah[4], bh4[4], al[4], bl[4];
#pragma unroll
    for (int i = 0; i < 4; i++) {
      ah[i] = *(const short8*)&As_hi[(wm + i * 16 + fr) * 32 + kq];
      bh4[i] = *(const short8*)&Bs_hi[(wn + i * 16 + fr) * 32 + kq];
      if constexpr (SPLIT) {
        al[i] = *(const short8*)&As_lo[(wm + i * 16 + fr) * 32 + kq];
        bl[i] = *(const short8*)&Bs_lo[(wn + i * 16 + fr) * 32 + kq];
      }
    }
#pragma unroll
    for (int mt = 0; mt < 4; mt++)
#pragma unroll
      for (int nt = 0; nt < 4; nt++) {
        acc[mt][nt] = __builtin_amdgcn_mfma_f32_16x16x32_bf16(
            __builtin_bit_cast(bf16x8, ah[mt]), __builtin_bit_cast(bf16x8, bh4[nt]),
            acc[mt][nt], 0, 0, 0);
        if constexpr (SPLIT) {
          acc[mt][nt] = __builtin_amdgcn_mfma_f32_16x16x32_bf16(
              __builtin_bit_cast(bf16x8, al[mt]), __builtin_bit_cast(bf16x8, bh4[nt]),
              acc[mt][nt], 0, 0, 0);
          acc[mt][nt] = __builtin_amdgcn_mfma_f32_16x16x32_bf16(
              __builtin_bit_cast(bf16x8, ah[mt]), __builtin_bit_cast(bf16x8, bl[nt]),
              acc[mt][nt], 0, 0, 0);
        }
      }
  }

  const int r0 = (lane >> 4) * 4;
  if constexpr (MODE == 3) {
    float pl[4][4];
#pragma unroll
    for (int mt = 0; mt < 4; mt++)
#pragma unroll
      for (int r = 0; r < 4; r++) pl[mt][r] = 0.f;
#pragma unroll
    for (int mt = 0; mt < 4; mt++)
#pragma unroll
      for (int nt = 0; nt < 4; nt++) {
        int col = n0 + wn + nt * 16 + fr;
        float bv = bias[col];
#pragma unroll
        for (int r = 0; r < 4; r++) {
          int row = m0 + wm + mt * 16 + r0 + r;
          float v = acc[mt][nt][r] + bv;
          pl[mt][r] += v * Xf[(size_t)row * 512 + col];
        }
      }
#pragma unroll
    for (int mt = 0; mt < 4; mt++)
#pragma unroll
      for (int r = 0; r < 4; r++) {
        float p = pl[mt][r];
        p += __shfl_xor(p, 1);
        p += __shfl_xor(p, 2);
        p += __shfl_xor(p, 4);
        p += __shfl_xor(p, 8);
        if (fr == r) {
          int row = m0 + wm + mt * 16 + r0 + r;
          atomicAdd(&s0[row], p);
        }
      }
    return;
  }
#pragma unroll
  for (int mt = 0; mt < 4; mt++) {
#pragma unroll
    for (int nt = 0; nt < 4; nt++) {
      int col = n0 + wn + nt * 16 + fr;
      float bv = 0.f;
      if constexpr (MODE == 0) bv = bias[col];
#pragma unroll
      for (int r = 0; r < 4; r++) {
        int row = m0 + wm + mt * 16 + r0 + r;
        float v = acc[mt][nt][r] + bv;
        if constexpr (MODE == 0) {
          if (col < 512) Cf[(size_t)row * 512 + col] = v;
          else Cb[(size_t)row * 896 + (col - 512)] = f2bf(v);
        } else if constexpr (MODE == 1) {
          Cb[(size_t)row * ldC + col] = f2bf(v);
        } else if constexpr (MODE == 2) {
          u16 h = f2bf(v);
          Cb[(size_t)row * ldC + col] = h;
          Cb2[(size_t)row * ldC + col] = f2bf(v - bf2f(h));
        } else if constexpr (MODE == 4) {
          size_t off = (size_t)row * ldC + col;
          Cf[off] += v;
        }
      }
    }
  }
}

// ---------------- fused gather / scores / softmax / aggregate ---------------
__global__ __launch_bounds__(256) void attn_kernel(
    const int* __restrict__ masks, const int* __restrict__ begins,
    const int* __restrict__ blens, const int* __restrict__ middles,
    const int* __restrict__ mlens, const int* __restrict__ ends,
    const int* __restrict__ elens, const float* __restrict__ emb,
    const float* __restrict__ HV, const u16* __restrict__ Pb,
    const float* __restrict__ gates, const float* __restrict__ b_begin,
    const float* __restrict__ b_middle, const float* __restrict__ b_end,
    const float* __restrict__ s0buf, const float* __restrict__ cbuf,
    float* __restrict__ out, u16* __restrict__ Ebar) {
  __shared__ float bvs[3][512];
  {
    int tt = threadIdx.x;
    for (int i = tt; i < 512; i += 256) {
      bvs[0][i] = b_begin[512 + i];
      bvs[1][i] = b_middle[512 + i];
      bvs[2][i] = b_end[512 + i];
    }
  }
  __syncthreads();
  const int t = threadIdx.x;
  const int lane = t & 63;
  const int wid = t >> 6;
  const int pos = blockIdx.x * 4 + wid;
  const int mask = masks[pos];
  const float* hvp = HV + (size_t)pos * 512;
  float4 hv0 = *(const float4*)(hvp + lane * 8);
  float4 hv1 = *(const float4*)(hvp + lane * 8 + 4);
  float* orow = out + (size_t)pos * 512;
  u16* erow = Ebar + (size_t)pos * 768;

  if (mask == 0) {
    // gates all zero -> lattice kv exactly 0; valid candidates -1e10,
    // invalid score 0; hidden unmasked.  out = w0*hv,  Ebar row = 0.
    float s0 = s0buf[pos] + cbuf[0];
    int nv = min(blens[pos], 5) + min(mlens[pos], 5) + min(elens[pos], 5);
    int ninv = 15 - nv;
    float w0;
    if (ninv == 0) {
      w0 = 1.f;
    } else {
      float Mx = fmaxf(s0, 0.f);
      float e0 = __expf(s0 - Mx);
      w0 = e0 / (e0 + (float)ninv * __expf(-Mx));
    }
    float4 o0, o1;
    o0.x = w0 * hv0.x; o0.y = w0 * hv0.y; o0.z = w0 * hv0.z; o0.w = w0 * hv0.w;
    o1.x = w0 * hv1.x; o1.y = w0 * hv1.y; o1.z = w0 * hv1.z; o1.w = w0 * hv1.w;
    *(float4*)(orow + lane * 8) = o0;
    *(float4*)(orow + lane * 8 + 4) = o1;
    ushort4 zz; zz.x = zz.y = zz.z = zz.w = 0;
    *(ushort4*)(erow + 0 * 256 + lane * 4) = zz;
    *(ushort4*)(erow + 1 * 256 + lane * 4) = zz;
    *(ushort4*)(erow + 2 * 256 + lane * 4) = zz;
  } else {
    float g[3];
    g[0] = gates[(size_t)pos * 3 + 0];
    g[1] = gates[(size_t)pos * 3 + 1];
    g[2] = gates[(size_t)pos * 3 + 2];
    const u16* prow = Pb + (size_t)pos * 896;
    float4 Pt[3];
    float qb[3];
#pragma unroll
    for (int ty = 0; ty < 3; ty++) {
      ushort4 pu = *(const ushort4*)(prow + ty * 256 + lane * 4);
      Pt[ty].x = bf2f(pu.x); Pt[ty].y = bf2f(pu.y);
      Pt[ty].z = bf2f(pu.z); Pt[ty].w = bf2f(pu.w);
      qb[ty] = bf2f(prow[768 + ty]);
    }
    int lens[3] = {blens[pos], mlens[pos], elens[pos]};
    const int* ib = begins + (size_t)pos * 5;
    const int* im = middles + (size_t)pos * 5;
    const int* ie = ends + (size_t)pos * 5;
    float4 ev[3][5];
#pragma unroll
    for (int w = 0; w < 5; w++) {
      ev[0][w] = *(const float4*)(emb + (size_t)ib[w] * 256 + lane * 4);
      ev[1][w] = *(const float4*)(emb + (size_t)im[w] * 256 + lane * 4);
      ev[2][w] = *(const float4*)(emb + (size_t)ie[w] * 256 + lane * 4);
    }
    float sc[16];
    sc[0] = -1e10f;  // hidden masked when mask != 0
#pragma unroll
    for (int ty = 0; ty < 3; ty++) {
#pragma unroll
      for (int w = 0; w < 5; w++) {
        float4 e = ev[ty][w];
        float d = Pt[ty].x * e.x + Pt[ty].y * e.y + Pt[ty].z * e.z + Pt[ty].w * e.w;
#pragma unroll
        for (int o = 32; o > 0; o >>= 1) d += __shfl_xor(d, o);
        sc[1 + ty * 5 + w] = (w < lens[ty]) ? -1e10f : g[ty] * (d + qb[ty]);
      }
    }
    float Mx = sc[0];
#pragma unroll
    for (int k = 1; k < 16; k++) Mx = fmaxf(Mx, sc[k]);
    float wts[16];
    float zs = 0.f;
#pragma unroll
    for (int k = 0; k < 16; k++) {
      wts[k] = __expf(sc[k] - Mx);
      zs += wts[k];
    }
    float inv = 1.f / zs;
    float alpha[3];
#pragma unroll
    for (int ty = 0; ty < 3; ty++) {
      float ax = 0.f, ay = 0.f, az = 0.f, aw = 0.f, asum = 0.f;
#pragma unroll
      for (int w = 0; w < 5; w++) {
        float wk = wts[1 + ty * 5 + w];
        asum += wk;
        ax += wk * ev[ty][w].x;
        ay += wk * ev[ty][w].y;
        az += wk * ev[ty][w].z;
        aw += wk * ev[ty][w].w;
      }
      float sg = g[ty] * inv;
      alpha[ty] = sg * asum;
      ushort4 h;
      h.x = f2bf(ax * sg); h.y = f2bf(ay * sg); h.z = f2bf(az * sg); h.w = f2bf(aw * sg);
      *(ushort4*)(erow + ty * 256 + lane * 4) = h;
    }
    float w0 = wts[0] * inv;
    float4 o0, o1;
    int hb = lane * 8;
    o0.x = w0 * hv0.x + alpha[0] * bvs[0][hb + 0] + alpha[1] * bvs[1][hb + 0] + alpha[2] * bvs[2][hb + 0];
    o0.y = w0 * hv0.y + alpha[0] * bvs[0][hb + 1] + alpha[1] * bvs[1][hb + 1] + alpha[2] * bvs[2][hb + 1];
    o0.z = w0 * hv0.z + alpha[0] * bvs[0][hb + 2] + alpha[1] * bvs[1][hb + 2] + alpha[2] * bvs[2][hb + 2];
    o0.w = w0 * hv0.w + alpha[0] * bvs[0][hb + 3] + alpha[1] * bvs[1][hb + 3] + alpha[2] * bvs[2][hb + 3];
    o1.x = w0 * hv1.x + alpha[0] * bvs[0][hb + 4] + alpha[1] * bvs[1][hb + 4] + alpha[2] * bvs[2][hb + 4];
    o1.y = w0 * hv1.y + alpha[0] * bvs[0][hb + 5] + alpha[1] * bvs[1][hb + 5] + alpha[2] * bvs[2][hb + 5];
    o1.z = w0 * hv1.z + alpha[0] * bvs[0][hb + 6] + alpha[1] * bvs[1][hb + 6] + alpha[2] * bvs[2][hb + 6];
    o1.w = w0 * hv1.w + alpha[0] * bvs[0][hb + 7] + alpha[1] * bvs[1][hb + 7] + alpha[2] * bvs[2][hb + 7];
    *(float4*)(orow + lane * 8) = o0;
    *(float4*)(orow + lane * 8 + 4) = o1;
  }
}

// ---------------------------------------------------------------------------
extern "C" void kernel_launch(void* const* d_in, const int* in_sizes, int n_in,
                              void* d_out, int out_size, void* d_ws, size_t ws_size,
                              hipStream_t stream) {
  const float* hiddens = (const float*)d_in[0];
  const int* masks = (const int*)d_in[1];
  const int* begins = (const int*)d_in[2];
  const int* blens = (const int*)d_in[3];
  const int* middles = (const int*)d_in[4];
  const int* mlens = (const int*)d_in[5];
  const int* ends = (const int*)d_in[6];
  const int* elens = (const int*)d_in[7];
  const float* emb = (const float*)d_in[8];
  const float* Wh = (const float*)d_in[9];
  const float* bh = (const float*)d_in[10];
  const float* Wb = (const float*)d_in[11];
  const float* bb = (const float*)d_in[12];
  const float* Wm = (const float*)d_in[13];
  const float* bm = (const float*)d_in[14];
  const float* We = (const float*)d_in[15];
  const float* be = (const float*)d_in[16];
  const float* Wg = (const float*)d_in[17];
  const float* bg = (const float*)d_in[18];
  float* out = (float*)d_out;

  char* ws = (char*)d_ws;
  size_t off = 0;
  auto alloc = [&](size_t bytes) -> char* {
    char* p = ws + off;
    off += (bytes + 255) & ~(size_t)255;
    return p;
  };
  u16* Xhi = (u16*)alloc((size_t)8192 * 512 * 2);
  u16* Xlo = (u16*)alloc((size_t)8192 * 512 * 2);
  u16* Whq_h = (u16*)alloc((size_t)512 * 512 * 2);
  u16* Whq_l = (u16*)alloc((size_t)512 * 512 * 2);
  u16* Whk_h = (u16*)alloc((size_t)512 * 512 * 2);
  u16* Whk_l = (u16*)alloc((size_t)512 * 512 * 2);
  u16* WkT = (u16*)alloc((size_t)896 * 512 * 2);
  u16* Wcat = (u16*)alloc((size_t)1408 * 512 * 2);   // [WhvT | Wcomb]
  u16* WvT = (u16*)alloc((size_t)512 * 768 * 2);
  u16* Mthi = (u16*)alloc((size_t)512 * 512 * 2);
  u16* Mtlo = (u16*)alloc((size_t)512 * 512 * 2);
  float* HV = (float*)alloc((size_t)8192 * 512 * 4);
  u16* Pb = (u16*)alloc((size_t)8192 * 896 * 2);
  float* lmr = (float*)alloc((size_t)8192 * 9 * 4);
  float* gates = (float*)alloc((size_t)8192 * 3 * 4);
  float* s0 = (float*)alloc((size_t)8192 * 4);
  float* bcat = (float*)alloc((size_t)1408 * 4);
  float* u = (float*)alloc((size_t)512 * 4);
  float* cbuf = (float*)alloc((size_t)4);
  u16* Ebar = (u16*)alloc((size_t)8192 * 768 * 2);
  if (off > ws_size) return;  // fail loudly (output stays poisoned)

  // 1) X split + lmr + s0 zero
  prep_xlmr<<<512, 256, 0, stream>>>(hiddens, Wg, bg, Xhi, Xlo, lmr, s0);
  // 2) weight preps + gates + bias dots
  prep_weights<<<712, 256, 0, stream>>>(Wh, Wb, Wm, We, bb, bm, be, bh, lmr, masks,
                                        Wcat, Whq_h, Whq_l, Whk_h, Whk_l, WkT, WvT,
                                        gates, bcat, u, cbuf);
  // 3) Mt[j,k] = sum_c Whk[j,c]*Whq[k,c]  (3-term split, split-bf16 out)
  gemm_k<2><<<dim3(4, 4), 256, 0, stream>>>(
      Whk_h, Whk_l, Whq_h, Whq_l, nullptr, nullptr, Mthi, Mtlo, 512, 512,
      nullptr, nullptr);
  // 4) Wcomb[n,k] = sum_c WkT[n,c]*Whq[k,c]  -> Wcat rows 512..1407 (bf16)
  gemm_k<1><<<dim3(7, 4), 256, 0, stream>>>(
      WkT, nullptr, Whq_h, nullptr, nullptr, nullptr, Wcat + (size_t)512 * 512,
      nullptr, 512, 512, nullptr, nullptr);
  // 5) s0[m] += sum_j (X@Mt^T + u)[m,j] * X[m,j]   (3-term split, reduce)
  gemm_k<3><<<dim3(64, 4), 256, 0, stream>>>(
      Xhi, Xlo, Mthi, Mtlo, u, nullptr, nullptr, nullptr, 512, 512,
      hiddens, s0);
  // 6) [HV | Pb] = X @ Wcat^T + bcat   (dual out)
  gemm_k<0><<<dim3(64, 11), 256, 0, stream>>>(
      Xhi, nullptr, Wcat, nullptr, bcat, HV, Pb, nullptr, 512, 512,
      nullptr, nullptr);
  // 7) fused attention
  attn_kernel<<<2048, 256, 0, stream>>>(masks, begins, blens, middles, mlens, ends,
                                        elens, emb, HV, Pb, gates, bb, bm, be,
                                        s0, cbuf, out, Ebar);
  // 8) out += Ebar @ WvT^T
  gemm_k<4><<<dim3(64, 4), 256, 0, stream>>>(
      Ebar, nullptr, WvT, nullptr, nullptr, out, nullptr, nullptr, 768, 512,
      nullptr, nullptr);
}

// Round 4
// 290.173 us; speedup vs baseline: 1.3943x; 1.3943x over previous
//
#include <hip/hip_runtime.h>
#include <cstdint>
#include <cstddef>

// ---------------------------------------------------------------------------
// GatedLatticeLayer on MI355X.  B=16 S=512 W=5 H=512 E=256 V=100000.
// MROWS = B*S = 8192.
//
// Structure (round 4): all-fp16 MFMA (no split), q/hk never materialized.
//   M[j,k]   = sum_c Whk[j,c] * Whq[k,c]            (512x512 fp16)
//   Wcomb[n,k] = sum_c WkT[n,c] * Whq[k,c]          (896x512 fp16)
//   s0[m]    = sum_j (X@M^T + u)[m,j] * X[m,j] + cb    (== q . hk, fp32)
//   [HV|Pb]  = X @ [WhvT|Wcomb]^T + bcat            (HV fp32, Pb fp16)
//   attn: score(t,w) = g_t*(P_t.emb[idx]+qb_t); out = w0*hv + sum alpha*bv
//   out     += Ebar @ WvT^T                          (Ebar fp16)
// 6 launches: prep_xlmr, prep_weights, gemmA(11x4), gemmB(64x15), attn, gemmC.
// ---------------------------------------------------------------------------

typedef unsigned short u16;
typedef _Float16 f16;
typedef __attribute__((ext_vector_type(8))) f16 f16x8;
typedef __attribute__((ext_vector_type(4))) float f32x4;

#define MROWS 8192
#define SS 512

static __device__ __forceinline__ u16 f2h(float x) {
  f16 h = (f16)x;
  return __builtin_bit_cast(u16, h);
}
static __device__ __forceinline__ float h2f(u16 h) {
  return (float)__builtin_bit_cast(f16, h);
}
static __device__ __forceinline__ float sigm(float x) { return 1.f / (1.f + __expf(-x)); }

static __device__ __forceinline__ void gl2lds(const u16* g, u16* l) {
  __builtin_amdgcn_global_load_lds(
      (const __attribute__((address_space(1))) unsigned int*)g,
      (__attribute__((address_space(3))) unsigned int*)l, 16, 0, 0);
}

// ---------------- prep: X -> fp16  +  lmr  +  s0 zero -----------------------
__global__ __launch_bounds__(256) void prep_xlmr(
    const float* __restrict__ X, const float* __restrict__ Wg,
    const float* __restrict__ bg, u16* __restrict__ Xh,
    float* __restrict__ lmr, float* __restrict__ s0) {
  __shared__ float wg[4608];
  const int t = threadIdx.x;
  if (blockIdx.x < 32) s0[blockIdx.x * 256 + t] = 0.f;
  for (int i = t; i < 4608; i += 256) wg[i] = Wg[i];
  __syncthreads();
  const int lane = t & 63, wid = t >> 6;
#pragma unroll
  for (int it = 0; it < 4; it++) {
    int pos = blockIdx.x * 16 + it * 4 + wid;
    const float* x = X + (size_t)pos * 512 + lane * 8;
    float4 x0 = *(const float4*)x;
    float4 x1 = *(const float4*)(x + 4);
    float xs[8] = {x0.x, x0.y, x0.z, x0.w, x1.x, x1.y, x1.z, x1.w};
    ushort4 h0, h1;
    h0.x = f2h(xs[0]); h0.y = f2h(xs[1]); h0.z = f2h(xs[2]); h0.w = f2h(xs[3]);
    h1.x = f2h(xs[4]); h1.y = f2h(xs[5]); h1.z = f2h(xs[6]); h1.w = f2h(xs[7]);
    ((ushort4*)Xh)[pos * 128 + lane * 2] = h0;
    ((ushort4*)Xh)[pos * 128 + lane * 2 + 1] = h1;
    float p[9];
#pragma unroll
    for (int c = 0; c < 9; c++) p[c] = 0.f;
    const float* wrow = wg + (lane * 8) * 9;
#pragma unroll
    for (int j = 0; j < 8; j++)
#pragma unroll
      for (int c = 0; c < 9; c++) p[c] += xs[j] * wrow[j * 9 + c];
#pragma unroll
    for (int c = 0; c < 9; c++)
#pragma unroll
      for (int o = 32; o > 0; o >>= 1) p[c] += __shfl_xor(p[c], o);
    if (lane == 0) {
#pragma unroll
      for (int c = 0; c < 9; c++) lmr[(size_t)pos * 9 + c] = p[c] + bg[c];
    }
  }
}

// ---------------- merged weight preps + gates + parallel bias dots ----------
// [0,64):    WhvT -> Breg rows 512..1023 (fp16)
// [64,128):  Whq (fp16)  +  Whk -> Acat rows 0..511 (fp16)
// [128,576): WkT -> Acat rows 512..1407 (fp16)
// [576,672): WvT (512x768 fp16)
// [672,704): gates (8192x3)
// [704,1059): wave-parallel dots: bcomb (bcat[512+n]), u, cb, bcat[0:512) copy
__global__ __launch_bounds__(256) void prep_weights(
    const float* __restrict__ Wh, const float* __restrict__ Wb,
    const float* __restrict__ Wm, const float* __restrict__ We,
    const float* __restrict__ bb, const float* __restrict__ bm,
    const float* __restrict__ be, const float* __restrict__ bh,
    const float* __restrict__ lmr, const int* __restrict__ masks,
    u16* __restrict__ Breg, u16* __restrict__ Acat, u16* __restrict__ Whq,
    u16* __restrict__ WvT, float* __restrict__ gates, float* __restrict__ bcat,
    float* __restrict__ u, float* __restrict__ cbuf) {
  __shared__ float tile[64][65];
  const int b = blockIdx.x;
  const int t = threadIdx.x;
  if (b < 64) {
    int k0 = (b & 7) * 64;
    int n0 = (b >> 3) * 64;
#pragma unroll
    for (int i = 0; i < 16; i++) {
      int li = i * 256 + t; int r = li >> 6, c = li & 63;
      tile[r][c] = Wh[(size_t)(k0 + r) * 1536 + 1024 + n0 + c];
    }
    __syncthreads();
#pragma unroll
    for (int i = 0; i < 16; i++) {
      int li = i * 256 + t; int r = li >> 6, c = li & 63;
      Breg[(size_t)(512 + n0 + r) * 512 + k0 + c] = f2h(tile[c][r]);
    }
  } else if (b < 128) {
#pragma unroll
    for (int i = 0; i < 4; i++) {
      int q4 = (b - 64) * 1024 + t * 4 + i;   // [0, 65536) float4 index
      int k = q4 >> 7;
      int c4 = (q4 & 127) * 4;
      float4 vq = *(const float4*)(Wh + (size_t)k * 1536 + c4);
      float4 vk = *(const float4*)(Wh + (size_t)k * 1536 + 512 + c4);
      ushort4 qh, kh;
      qh.x = f2h(vq.x); qh.y = f2h(vq.y); qh.z = f2h(vq.z); qh.w = f2h(vq.w);
      kh.x = f2h(vk.x); kh.y = f2h(vk.y); kh.z = f2h(vk.z); kh.w = f2h(vk.w);
      size_t o = (size_t)k * 512 + c4;
      *(ushort4*)(Whq + o) = qh;
      *(ushort4*)(Acat + o) = kh;
    }
  } else if (b < 576) {
    int tid = (b - 128) * 256 + t;      // [0, 896*128)
    int n = tid >> 7;
    int kq = (tid & 127) * 4;
    float4 v;
    if (n < 768) {
      int ty = n >> 8, c = n & 255;
      const float* src = (ty == 0 ? Wb : ty == 1 ? Wm : We) + (size_t)c * 1024 + kq;
      v = *(const float4*)src;
    } else if (n < 771) {
      int ty = n - 768;
      const float* src = (ty == 0 ? bb : ty == 1 ? bm : be) + kq;
      v = *(const float4*)src;
    } else {
      v = make_float4(0.f, 0.f, 0.f, 0.f);
    }
    ushort4 h; h.x = f2h(v.x); h.y = f2h(v.y); h.z = f2h(v.z); h.w = f2h(v.w);
    ((ushort4*)(Acat + (size_t)512 * 512))[tid] = h;
  } else if (b < 672) {
    int idx = b - 576;                  // [0,96)
    int ty = idx >> 5;
    int rem = idx & 31;
    int c0 = (rem & 3) * 64;
    int n0 = (rem >> 2) * 64;
    const float* Wsrc = ty == 0 ? Wb : ty == 1 ? Wm : We;
#pragma unroll
    for (int i = 0; i < 16; i++) {
      int li = i * 256 + t; int r = li >> 6, c = li & 63;
      tile[r][c] = Wsrc[(size_t)(c0 + r) * 1024 + 512 + n0 + c];
    }
    __syncthreads();
#pragma unroll
    for (int i = 0; i < 16; i++) {
      int li = i * 256 + t; int r = li >> 6, c = li & 63;
      WvT[(size_t)(n0 + r) * 768 + ty * 256 + c0 + c] = f2h(tile[c][r]);
    }
  } else if (b < 704) {
    int pos = (b - 672) * 256 + t;      // [0,8192)
    int s = pos & (SS - 1);
    float g0, g1, g2;
    if (masks[pos] == 0) {
      g0 = g1 = g2 = 0.f;
    } else if (s == 0 || s == SS - 1) {
      g0 = 1.f; g1 = 0.f; g2 = 1.f;
    } else {
      const float* p0 = lmr + (size_t)(pos - 1) * 9;
      const float* p1 = lmr + (size_t)pos * 9;
      const float* p2 = lmr + (size_t)(pos + 1) * 9;
      g0 = sigm(p0[0] + p1[3] + p2[6]);
      g1 = sigm(p0[1] + p1[4] + p2[7]);
      g2 = sigm(p0[2] + p1[5] + p2[8]);
    }
    gates[(size_t)pos * 3 + 0] = g0;
    gates[(size_t)pos * 3 + 1] = g1;
    gates[(size_t)pos * 3 + 2] = g2;
  } else {
    // wave-parallel dots: one wave per output scalar.
    const int lane = t & 63;
    const int widx = (b - 704) * 4 + (t >> 6);   // [0,1420)
    const int c = lane * 8;
    if (widx < 896) {
      // bcat[512+n] = sum_c bh_q[c] * WkT_f32[n][c]
      int n = widx;
      float acc = 0.f;
      if (n < 768) {
        int ty = n >> 8, ce = n & 255;
        const float* src = (ty == 0 ? Wb : ty == 1 ? Wm : We) + (size_t)ce * 1024 + c;
        float4 a0 = *(const float4*)src;
        float4 a1 = *(const float4*)(src + 4);
        float4 b0 = *(const float4*)(bh + c);
        float4 b1 = *(const float4*)(bh + c + 4);
        acc = a0.x * b0.x + a0.y * b0.y + a0.z * b0.z + a0.w * b0.w +
              a1.x * b1.x + a1.y * b1.y + a1.z * b1.z + a1.w * b1.w;
      } else if (n < 771) {
        int ty = n - 768;
        const float* src = (ty == 0 ? bb : ty == 1 ? bm : be) + c;
        float4 a0 = *(const float4*)src;
        float4 a1 = *(const float4*)(src + 4);
        float4 b0 = *(const float4*)(bh + c);
        float4 b1 = *(const float4*)(bh + c + 4);
        acc = a0.x * b0.x + a0.y * b0.y + a0.z * b0.z + a0.w * b0.w +
              a1.x * b1.x + a1.y * b1.y + a1.z * b1.z + a1.w * b1.w;
      }
#pragma unroll
      for (int o = 32; o > 0; o >>= 1) acc += __shfl_xor(acc, o);
      if (lane == 0) bcat[512 + n] = acc;
    } else if (widx < 1408) {
      // u[k] = sum_c Wh[k][c]*bh[512+c] + Wh[k][512+c]*bh[c]
      int k = widx - 896;
      const float* wr = Wh + (size_t)k * 1536;
      float4 a0 = *(const float4*)(wr + c);
      float4 a1 = *(const float4*)(wr + c + 4);
      float4 a2 = *(const float4*)(wr + 512 + c);
      float4 a3 = *(const float4*)(wr + 512 + c + 4);
      float4 b0 = *(const float4*)(bh + 512 + c);
      float4 b1 = *(const float4*)(bh + 512 + c + 4);
      float4 b2 = *(const float4*)(bh + c);
      float4 b3 = *(const float4*)(bh + c + 4);
      float acc = a0.x * b0.x + a0.y * b0.y + a0.z * b0.z + a0.w * b0.w +
                  a1.x * b1.x + a1.y * b1.y + a1.z * b1.z + a1.w * b1.w +
                  a2.x * b2.x + a2.y * b2.y + a2.z * b2.z + a2.w * b2.w +
                  a3.x * b3.x + a3.y * b3.y + a3.z * b3.z + a3.w * b3.w;
#pragma unroll
      for (int o = 32; o > 0; o >>= 1) acc += __shfl_xor(acc, o);
      if (lane == 0) u[k] = acc;
    } else if (widx == 1408) {
      float4 b0 = *(const float4*)(bh + c);
      float4 b1 = *(const float4*)(bh + c + 4);
      float4 b2 = *(const float4*)(bh + 512 + c);
      float4 b3 = *(const float4*)(bh + 512 + c + 4);
      float acc = b0.x * b2.x + b0.y * b2.y + b0.z * b2.z + b0.w * b2.w +
                  b1.x * b3.x + b1.y * b3.y + b1.z * b3.z + b1.w * b3.w;
#pragma unroll
      for (int o = 32; o > 0; o >>= 1) acc += __shfl_xor(acc, o);
      if (lane == 0) cbuf[0] = acc;
    } else if (widx < 1417) {
      int i = (widx - 1409) * 64 + lane;   // [0,512)
      bcat[i] = bh[1024 + i];
    }
  }
}

// ---------------- unified fp16 MFMA GEMM ------------------------------------
// 128x128 tile, 4 waves (2x2), each 4x4 of 16x16x32 f16 MFMA, gl2lds staging.
// MODE 0 (gemmB, grid 64x15): y<4: s0[row] += sum_col (acc+u[col])*Xf[row,col]
//                             y>=4: col=n0-512+...; col<512 -> HV fp32 +bcat
//                                                   else Pb fp16 (ld896) +bcat
// MODE 1 (gemmA): out fp16 Cb ld512; row >= 512 remapped to row+512 (Wcomb)
// MODE 2 (gemmC): Cf[row*512+col] += acc
template <int MODE>
__global__ __launch_bounds__(256) void gemm_k(
    const u16* __restrict__ A, const u16* __restrict__ Bt,
    const float* __restrict__ ubias, const float* __restrict__ bcat,
    float* __restrict__ Cf, u16* __restrict__ Cb, int Kdim,
    const float* __restrict__ Xf, float* __restrict__ s0) {
  __shared__ __align__(16) u16 As[128 * 32];
  __shared__ __align__(16) u16 Bs[128 * 32];

  const int t = threadIdx.x;
  const int lane = t & 63;
  const int wid = t >> 6;
  const int m0 = blockIdx.x * 128;
  const int n0 = blockIdx.y * 128;
  const int wm = (wid & 1) * 64;
  const int wn = (wid >> 1) * 64;
  const int fr = lane & 15;
  const int kq = (lane >> 4) * 8;

  f32x4 acc[4][4];
#pragma unroll
  for (int i = 0; i < 4; i++)
#pragma unroll
    for (int j = 0; j < 4; j++) acc[i][j] = (f32x4){0.f, 0.f, 0.f, 0.f};

  for (int k0 = 0; k0 < Kdim; k0 += 32) {
    __syncthreads();
#pragma unroll
    for (int p = 0; p < 2; p++) {
      int li = p * 256 + t;
      int row = li >> 2;
      int so = (li & 3) * 8;
      gl2lds(&A[(size_t)(m0 + row) * Kdim + k0 + so], &As[li * 8]);
      gl2lds(&Bt[(size_t)(n0 + row) * Kdim + k0 + so], &Bs[li * 8]);
    }
    __syncthreads();
    f16x8 av[4], bv[4];
#pragma unroll
    for (int i = 0; i < 4; i++) {
      av[i] = *(const f16x8*)&As[(wm + i * 16 + fr) * 32 + kq];
      bv[i] = *(const f16x8*)&Bs[(wn + i * 16 + fr) * 32 + kq];
    }
#pragma unroll
    for (int mt = 0; mt < 4; mt++)
#pragma unroll
      for (int nt = 0; nt < 4; nt++)
        acc[mt][nt] = __builtin_amdgcn_mfma_f32_16x16x32_f16(
            av[mt], bv[nt], acc[mt][nt], 0, 0, 0);
  }

  const int r0 = (lane >> 4) * 4;
  if constexpr (MODE == 0) {
    if (blockIdx.y < 4) {
      // s0 epilogue: rowdot with fp32 X
      float pl[4][4];
#pragma unroll
      for (int mt = 0; mt < 4; mt++)
#pragma unroll
        for (int r = 0; r < 4; r++) pl[mt][r] = 0.f;
#pragma unroll
      for (int mt = 0; mt < 4; mt++)
#pragma unroll
        for (int nt = 0; nt < 4; nt++) {
          int col = n0 + wn + nt * 16 + fr;
          float bv2 = ubias[col];
#pragma unroll
          for (int r = 0; r < 4; r++) {
            int row = m0 + wm + mt * 16 + r0 + r;
            pl[mt][r] += (acc[mt][nt][r] + bv2) * Xf[(size_t)row * 512 + col];
          }
        }
#pragma unroll
      for (int mt = 0; mt < 4; mt++)
#pragma unroll
        for (int r = 0; r < 4; r++) {
          float p = pl[mt][r];
          p += __shfl_xor(p, 1);
          p += __shfl_xor(p, 2);
          p += __shfl_xor(p, 4);
          p += __shfl_xor(p, 8);
          if (fr == r) {
            int row = m0 + wm + mt * 16 + r0 + r;
            atomicAdd(&s0[row], p);
          }
        }
      return;
    }
#pragma unroll
    for (int mt = 0; mt < 4; mt++)
#pragma unroll
      for (int nt = 0; nt < 4; nt++) {
        int col = n0 - 512 + wn + nt * 16 + fr;
        float bv2 = bcat[col];
#pragma unroll
        for (int r = 0; r < 4; r++) {
          int row = m0 + wm + mt * 16 + r0 + r;
          float v = acc[mt][nt][r] + bv2;
          if (col < 512) Cf[(size_t)row * 512 + col] = v;
          else Cb[(size_t)row * 896 + (col - 512)] = f2h(v);
        }
      }
  } else if constexpr (MODE == 1) {
#pragma unroll
    for (int mt = 0; mt < 4; mt++)
#pragma unroll
      for (int nt = 0; nt < 4; nt++) {
        int col = n0 + wn + nt * 16 + fr;
#pragma unroll
        for (int r = 0; r < 4; r++) {
          int row = m0 + wm + mt * 16 + r0 + r;
          int orow = row < 512 ? row : row + 512;   // Wcomb rows -> 1024..1919
          Cb[(size_t)orow * 512 + col] = f2h(acc[mt][nt][r]);
        }
      }
  } else {
#pragma unroll
    for (int mt = 0; mt < 4; mt++)
#pragma unroll
      for (int nt = 0; nt < 4; nt++) {
        int col = n0 + wn + nt * 16 + fr;
#pragma unroll
        for (int r = 0; r < 4; r++) {
          int row = m0 + wm + mt * 16 + r0 + r;
          Cf[(size_t)row * 512 + col] += acc[mt][nt][r];
        }
      }
  }
}

// ---------------- fused gather / scores / softmax / aggregate ---------------
__global__ __launch_bounds__(256) void attn_kernel(
    const int* __restrict__ masks, const int* __restrict__ begins,
    const int* __restrict__ blens, const int* __restrict__ middles,
    const int* __restrict__ mlens, const int* __restrict__ ends,
    const int* __restrict__ elens, const float* __restrict__ emb,
    const float* __restrict__ HV, const u16* __restrict__ Pb,
    const float* __restrict__ gates, const float* __restrict__ b_begin,
    const float* __restrict__ b_middle, const float* __restrict__ b_end,
    const float* __restrict__ s0buf, const float* __restrict__ cbuf,
    float* __restrict__ out, u16* __restrict__ Ebar) {
  __shared__ float bvs[3][512];
  {
    int tt = threadIdx.x;
    for (int i = tt; i < 512; i += 256) {
      bvs[0][i] = b_begin[512 + i];
      bvs[1][i] = b_middle[512 + i];
      bvs[2][i] = b_end[512 + i];
    }
  }
  __syncthreads();
  const int t = threadIdx.x;
  const int lane = t & 63;
  const int wid = t >> 6;
  const int pos = blockIdx.x * 4 + wid;
  const int mask = masks[pos];
  const float* hvp = HV + (size_t)pos * 512;
  float4 hv0 = *(const float4*)(hvp + lane * 8);
  float4 hv1 = *(const float4*)(hvp + lane * 8 + 4);
  float* orow = out + (size_t)pos * 512;
  u16* erow = Ebar + (size_t)pos * 768;

  if (mask == 0) {
    // gates all zero -> lattice kv exactly 0; valid candidates -1e10,
    // invalid score 0; hidden unmasked.  out = w0*hv,  Ebar row = 0.
    float s0 = s0buf[pos] + cbuf[0];
    int nv = min(blens[pos], 5) + min(mlens[pos], 5) + min(elens[pos], 5);
    int ninv = 15 - nv;
    float w0;
    if (ninv == 0) {
      w0 = 1.f;
    } else {
      float Mx = fmaxf(s0, 0.f);
      float e0 = __expf(s0 - Mx);
      w0 = e0 / (e0 + (float)ninv * __expf(-Mx));
    }
    float4 o0, o1;
    o0.x = w0 * hv0.x; o0.y = w0 * hv0.y; o0.z = w0 * hv0.z; o0.w = w0 * hv0.w;
    o1.x = w0 * hv1.x; o1.y = w0 * hv1.y; o1.z = w0 * hv1.z; o1.w = w0 * hv1.w;
    *(float4*)(orow + lane * 8) = o0;
    *(float4*)(orow + lane * 8 + 4) = o1;
    ushort4 zz; zz.x = zz.y = zz.z = zz.w = 0;
    *(ushort4*)(erow + 0 * 256 + lane * 4) = zz;
    *(ushort4*)(erow + 1 * 256 + lane * 4) = zz;
    *(ushort4*)(erow + 2 * 256 + lane * 4) = zz;
  } else {
    float g[3];
    g[0] = gates[(size_t)pos * 3 + 0];
    g[1] = gates[(size_t)pos * 3 + 1];
    g[2] = gates[(size_t)pos * 3 + 2];
    const u16* prow = Pb + (size_t)pos * 896;
    float4 Pt[3];
    float qb[3];
#pragma unroll
    for (int ty = 0; ty < 3; ty++) {
      ushort4 pu = *(const ushort4*)(prow + ty * 256 + lane * 4);
      Pt[ty].x = h2f(pu.x); Pt[ty].y = h2f(pu.y);
      Pt[ty].z = h2f(pu.z); Pt[ty].w = h2f(pu.w);
      qb[ty] = h2f(prow[768 + ty]);
    }
    int lens[3] = {blens[pos], mlens[pos], elens[pos]};
    const int* ib = begins + (size_t)pos * 5;
    const int* im = middles + (size_t)pos * 5;
    const int* ie = ends + (size_t)pos * 5;
    float4 ev[3][5];
#pragma unroll
    for (int w = 0; w < 5; w++) {
      ev[0][w] = *(const float4*)(emb + (size_t)ib[w] * 256 + lane * 4);
      ev[1][w] = *(const float4*)(emb + (size_t)im[w] * 256 + lane * 4);
      ev[2][w] = *(const float4*)(emb + (size_t)ie[w] * 256 + lane * 4);
    }
    float sc[16];
    sc[0] = -1e10f;  // hidden masked when mask != 0
#pragma unroll
    for (int ty = 0; ty < 3; ty++) {
#pragma unroll
      for (int w = 0; w < 5; w++) {
        float4 e = ev[ty][w];
        float d = Pt[ty].x * e.x + Pt[ty].y * e.y + Pt[ty].z * e.z + Pt[ty].w * e.w;
#pragma unroll
        for (int o = 32; o > 0; o >>= 1) d += __shfl_xor(d, o);
        sc[1 + ty * 5 + w] = (w < lens[ty]) ? -1e10f : g[ty] * (d + qb[ty]);
      }
    }
    float Mx = sc[0];
#pragma unroll
    for (int k = 1; k < 16; k++) Mx = fmaxf(Mx, sc[k]);
    float wts[16];
    float zs = 0.f;
#pragma unroll
    for (int k = 0; k < 16; k++) {
      wts[k] = __expf(sc[k] - Mx);
      zs += wts[k];
    }
    float inv = 1.f / zs;
    float alpha[3];
#pragma unroll
    for (int ty = 0; ty < 3; ty++) {
      float ax = 0.f, ay = 0.f, az = 0.f, aw = 0.f, asum = 0.f;
#pragma unroll
      for (int w = 0; w < 5; w++) {
        float wk = wts[1 + ty * 5 + w];
        asum += wk;
        ax += wk * ev[ty][w].x;
        ay += wk * ev[ty][w].y;
        az += wk * ev[ty][w].z;
        aw += wk * ev[ty][w].w;
      }
      float sg = g[ty] * inv;
      alpha[ty] = sg * asum;
      ushort4 h;
      h.x = f2h(ax * sg); h.y = f2h(ay * sg); h.z = f2h(az * sg); h.w = f2h(aw * sg);
      *(ushort4*)(erow + ty * 256 + lane * 4) = h;
    }
    float w0 = wts[0] * inv;
    float4 o0, o1;
    int hb = lane * 8;
    o0.x = w0 * hv0.x + alpha[0] * bvs[0][hb + 0] + alpha[1] * bvs[1][hb + 0] + alpha[2] * bvs[2][hb + 0];
    o0.y = w0 * hv0.y + alpha[0] * bvs[0][hb + 1] + alpha[1] * bvs[1][hb + 1] + alpha[2] * bvs[2][hb + 1];
    o0.z = w0 * hv0.z + alpha[0] * bvs[0][hb + 2] + alpha[1] * bvs[1][hb + 2] + alpha[2] * bvs[2][hb + 2];
    o0.w = w0 * hv0.w + alpha[0] * bvs[0][hb + 3] + alpha[1] * bvs[1][hb + 3] + alpha[2] * bvs[2][hb + 3];
    o1.x = w0 * hv1.x + alpha[0] * bvs[0][hb + 4] + alpha[1] * bvs[1][hb + 4] + alpha[2] * bvs[2][hb + 4];
    o1.y = w0 * hv1.y + alpha[0] * bvs[0][hb + 5] + alpha[1] * bvs[1][hb + 5] + alpha[2] * bvs[2][hb + 5];
    o1.z = w0 * hv1.z + alpha[0] * bvs[0][hb + 6] + alpha[1] * bvs[1][hb + 6] + alpha[2] * bvs[2][hb + 6];
    o1.w = w0 * hv1.w + alpha[0] * bvs[0][hb + 7] + alpha[1] * bvs[1][hb + 7] + alpha[2] * bvs[2][hb + 7];
    *(float4*)(orow + lane * 8) = o0;
    *(float4*)(orow + lane * 8 + 4) = o1;
  }
}

// ---------------------------------------------------------------------------
extern "C" void kernel_launch(void* const* d_in, const int* in_sizes, int n_in,
                              void* d_out, int out_size, void* d_ws, size_t ws_size,
                              hipStream_t stream) {
  const float* hiddens = (const float*)d_in[0];
  const int* masks = (const int*)d_in[1];
  const int* begins = (const int*)d_in[2];
  const int* blens = (const int*)d_in[3];
  const int* middles = (const int*)d_in[4];
  const int* mlens = (const int*)d_in[5];
  const int* ends = (const int*)d_in[6];
  const int* elens = (const int*)d_in[7];
  const float* emb = (const float*)d_in[8];
  const float* Wh = (const float*)d_in[9];
  const float* bh = (const float*)d_in[10];
  const float* Wb = (const float*)d_in[11];
  const float* bb = (const float*)d_in[12];
  const float* Wm = (const float*)d_in[13];
  const float* bm = (const float*)d_in[14];
  const float* We = (const float*)d_in[15];
  const float* be = (const float*)d_in[16];
  const float* Wg = (const float*)d_in[17];
  const float* bg = (const float*)d_in[18];
  float* out = (float*)d_out;

  char* ws = (char*)d_ws;
  size_t off = 0;
  auto alloc = [&](size_t bytes) -> char* {
    char* p = ws + off;
    off += (bytes + 255) & ~(size_t)255;
    return p;
  };
  u16* Xh = (u16*)alloc((size_t)8192 * 512 * 2);
  u16* Whq = (u16*)alloc((size_t)512 * 512 * 2);
  u16* Acat = (u16*)alloc((size_t)1408 * 512 * 2);   // [Whk | WkT]
  u16* Breg = (u16*)alloc((size_t)1920 * 512 * 2);   // [M | WhvT | Wcomb]
  u16* WvT = (u16*)alloc((size_t)512 * 768 * 2);
  float* HV = (float*)alloc((size_t)8192 * 512 * 4);
  u16* Pb = (u16*)alloc((size_t)8192 * 896 * 2);
  float* lmr = (float*)alloc((size_t)8192 * 9 * 4);
  float* gates = (float*)alloc((size_t)8192 * 3 * 4);
  float* s0 = (float*)alloc((size_t)8192 * 4);
  float* bcat = (float*)alloc((size_t)1408 * 4);
  float* u = (float*)alloc((size_t)512 * 4);
  float* cbuf = (float*)alloc((size_t)4);
  u16* Ebar = (u16*)alloc((size_t)8192 * 768 * 2);
  if (off > ws_size) return;  // fail loudly (output stays poisoned)

  // 1) X -> fp16, lmr, s0 zero
  prep_xlmr<<<512, 256, 0, stream>>>(hiddens, Wg, bg, Xh, lmr, s0);
  // 2) weight preps + gates + parallel bias dots
  prep_weights<<<1059, 256, 0, stream>>>(Wh, Wb, Wm, We, bb, bm, be, bh, lmr,
                                         masks, Breg, Acat, Whq, WvT, gates,
                                         bcat, u, cbuf);
  // 3) gemmA: Breg[M rows 0..511; Wcomb rows 1024..1919] = Acat @ Whq^T
  gemm_k<1><<<dim3(11, 4), 256, 0, stream>>>(
      Acat, Whq, nullptr, nullptr, nullptr, Breg, 512, nullptr, nullptr);
  // 4) gemmB: y<4 -> s0; y>=4 -> [HV|Pb] = Xh @ [WhvT|Wcomb]^T + bcat
  gemm_k<0><<<dim3(64, 15), 256, 0, stream>>>(
      Xh, Breg, u, bcat, HV, Pb, 512, hiddens, s0);
  // 5) fused attention
  attn_kernel<<<2048, 256, 0, stream>>>(masks, begins, blens, middles, mlens, ends,
                                        elens, emb, HV, Pb, gates, bb, bm, be,
                                        s0, cbuf, out, Ebar);
  // 6) gemmC: out += Ebar @ WvT^T
  gemm_k<2><<<dim3(64, 4), 256, 0, stream>>>(
      Ebar, WvT, nullptr, nullptr, out, nullptr, 768, nullptr, nullptr);
}

// Round 5
// 287.957 us; speedup vs baseline: 1.4050x; 1.0077x over previous
//
#include <hip/hip_runtime.h>
#include <cstdint>
#include <cstddef>

// ---------------------------------------------------------------------------
// GatedLatticeLayer on MI355X.  B=16 S=512 W=5 H=512 E=256 V=100000.
// MROWS = B*S = 8192.
//
// Round 5 structure (5 launches), all-fp16 MFMA:
//   prep_all: X->fp16, lmr, weight transposes/copies, wave-parallel bias dots
//   gemmA:    Breg[M | (WhvT) | Wcomb] = Acat @ Whq^T     (fp16)
//   gemmB:    y<4: s0[m] += rowdot(Xh@M^T + u, Xh); y>=4: HPb = Xh@[WhvT|Wcomb]^T+bcat
//   attn:     only INVALID candidates (w>=len) survive the reference mask
//             (valid ones get -1e10 -> weight 0) -> gather only those;
//             deg case (all 15 valid, mask!=0) -> uniform 1/16 weights.
//             emits {w0,a0,a1,a2} + Ebar only.
//   gemmC:    out = w0*hv + sum_t a_t*bv_t + Ebar @ WvT^T
// ---------------------------------------------------------------------------

typedef unsigned short u16;
typedef _Float16 f16;
typedef __attribute__((ext_vector_type(8))) f16 f16x8;
typedef __attribute__((ext_vector_type(4))) float f32x4;

#define MROWS 8192
#define SS 512

static __device__ __forceinline__ u16 f2h(float x) {
  f16 h = (f16)x;
  return __builtin_bit_cast(u16, h);
}
static __device__ __forceinline__ float h2f(u16 h) {
  return (float)__builtin_bit_cast(f16, h);
}
static __device__ __forceinline__ float sigm(float x) { return 1.f / (1.f + __expf(-x)); }

static __device__ __forceinline__ void gl2lds(const u16* g, u16* l) {
  __builtin_amdgcn_global_load_lds(
      (const __attribute__((address_space(1))) unsigned int*)g,
      (__attribute__((address_space(3))) unsigned int*)l, 16, 0, 0);
}

// ---------------- merged prep: weights + dots + X/lmr ----------------------
// [0,64):      WhvT -> Breg rows 512..1023 (fp16)
// [64,128):    Whq (fp16) + Whk -> Acat rows 0..511
// [128,576):   WkT -> Acat rows 512..1407
// [576,672):   WvT (512x768 fp16)
// [672,1028):  wave dots: bcat[512+n]=bcomb, u, cb, bcat[0:512) copy
// [1028,1540): X -> fp16 + lmr (+ s0 zero)
__global__ __launch_bounds__(256) void prep_all(
    const float* __restrict__ X, const float* __restrict__ Wg,
    const float* __restrict__ bg, const float* __restrict__ Wh,
    const float* __restrict__ Wb, const float* __restrict__ Wm,
    const float* __restrict__ We, const float* __restrict__ bb,
    const float* __restrict__ bm, const float* __restrict__ be,
    const float* __restrict__ bh, u16* __restrict__ Xh,
    float* __restrict__ lmr, float* __restrict__ s0, u16* __restrict__ Breg,
    u16* __restrict__ Acat, u16* __restrict__ Whq, u16* __restrict__ WvT,
    float* __restrict__ bcat, float* __restrict__ u, float* __restrict__ cbuf) {
  __shared__ float shmem[4608];            // tile (64x65=4160) or wg (4608)
#define TI(r, c) shmem[(r)*65 + (c)]
  const int b = blockIdx.x;
  const int t = threadIdx.x;
  if (b < 64) {
    int k0 = (b & 7) * 64;
    int n0 = (b >> 3) * 64;
#pragma unroll
    for (int i = 0; i < 16; i++) {
      int li = i * 256 + t; int r = li >> 6, c = li & 63;
      TI(r, c) = Wh[(size_t)(k0 + r) * 1536 + 1024 + n0 + c];
    }
    __syncthreads();
#pragma unroll
    for (int i = 0; i < 16; i++) {
      int li = i * 256 + t; int r = li >> 6, c = li & 63;
      Breg[(size_t)(512 + n0 + r) * 512 + k0 + c] = f2h(TI(c, r));
    }
  } else if (b < 128) {
#pragma unroll
    for (int i = 0; i < 4; i++) {
      int q4 = (b - 64) * 1024 + t * 4 + i;   // [0, 65536) float4 index
      int k = q4 >> 7;
      int c4 = (q4 & 127) * 4;
      float4 vq = *(const float4*)(Wh + (size_t)k * 1536 + c4);
      float4 vk = *(const float4*)(Wh + (size_t)k * 1536 + 512 + c4);
      ushort4 qh, kh;
      qh.x = f2h(vq.x); qh.y = f2h(vq.y); qh.z = f2h(vq.z); qh.w = f2h(vq.w);
      kh.x = f2h(vk.x); kh.y = f2h(vk.y); kh.z = f2h(vk.z); kh.w = f2h(vk.w);
      size_t o = (size_t)k * 512 + c4;
      *(ushort4*)(Whq + o) = qh;
      *(ushort4*)(Acat + o) = kh;
    }
  } else if (b < 576) {
    int tid = (b - 128) * 256 + t;      // [0, 896*128)
    int n = tid >> 7;
    int kq = (tid & 127) * 4;
    float4 v;
    if (n < 768) {
      int ty = n >> 8, c = n & 255;
      const float* src = (ty == 0 ? Wb : ty == 1 ? Wm : We) + (size_t)c * 1024 + kq;
      v = *(const float4*)src;
    } else if (n < 771) {
      int ty = n - 768;
      const float* src = (ty == 0 ? bb : ty == 1 ? bm : be) + kq;
      v = *(const float4*)src;
    } else {
      v = make_float4(0.f, 0.f, 0.f, 0.f);
    }
    ushort4 h; h.x = f2h(v.x); h.y = f2h(v.y); h.z = f2h(v.z); h.w = f2h(v.w);
    ((ushort4*)(Acat + (size_t)512 * 512))[tid] = h;
  } else if (b < 672) {
    int idx = b - 576;                  // [0,96)
    int ty = idx >> 5;
    int rem = idx & 31;
    int c0 = (rem & 3) * 64;
    int n0 = (rem >> 2) * 64;
    const float* Wsrc = ty == 0 ? Wb : ty == 1 ? Wm : We;
#pragma unroll
    for (int i = 0; i < 16; i++) {
      int li = i * 256 + t; int r = li >> 6, c = li & 63;
      TI(r, c) = Wsrc[(size_t)(c0 + r) * 1024 + 512 + n0 + c];
    }
    __syncthreads();
#pragma unroll
    for (int i = 0; i < 16; i++) {
      int li = i * 256 + t; int r = li >> 6, c = li & 63;
      WvT[(size_t)(n0 + r) * 768 + ty * 256 + c0 + c] = f2h(TI(c, r));
    }
  } else if (b < 1028) {
    // wave-parallel dots: one wave per output scalar.
    const int lane = t & 63;
    const int widx = (b - 672) * 4 + (t >> 6);   // [0,1424)
    const int c = lane * 8;
    if (widx < 896) {
      int n = widx;
      float acc = 0.f;
      if (n < 771) {
        const float* src;
        if (n < 768) {
          int ty = n >> 8, ce = n & 255;
          src = (ty == 0 ? Wb : ty == 1 ? Wm : We) + (size_t)ce * 1024 + c;
        } else {
          int ty = n - 768;
          src = (ty == 0 ? bb : ty == 1 ? bm : be) + c;
        }
        float4 a0 = *(const float4*)src;
        float4 a1 = *(const float4*)(src + 4);
        float4 b0 = *(const float4*)(bh + c);
        float4 b1 = *(const float4*)(bh + c + 4);
        acc = a0.x * b0.x + a0.y * b0.y + a0.z * b0.z + a0.w * b0.w +
              a1.x * b1.x + a1.y * b1.y + a1.z * b1.z + a1.w * b1.w;
      }
#pragma unroll
      for (int o = 32; o > 0; o >>= 1) acc += __shfl_xor(acc, o);
      if (lane == 0) bcat[512 + n] = acc;
    } else if (widx < 1408) {
      int k = widx - 896;
      const float* wr = Wh + (size_t)k * 1536;
      float4 a0 = *(const float4*)(wr + c);
      float4 a1 = *(const float4*)(wr + c + 4);
      float4 a2 = *(const float4*)(wr + 512 + c);
      float4 a3 = *(const float4*)(wr + 512 + c + 4);
      float4 b0 = *(const float4*)(bh + 512 + c);
      float4 b1 = *(const float4*)(bh + 512 + c + 4);
      float4 b2 = *(const float4*)(bh + c);
      float4 b3 = *(const float4*)(bh + c + 4);
      float acc = a0.x * b0.x + a0.y * b0.y + a0.z * b0.z + a0.w * b0.w +
                  a1.x * b1.x + a1.y * b1.y + a1.z * b1.z + a1.w * b1.w +
                  a2.x * b2.x + a2.y * b2.y + a2.z * b2.z + a2.w * b2.w +
                  a3.x * b3.x + a3.y * b3.y + a3.z * b3.z + a3.w * b3.w;
#pragma unroll
      for (int o = 32; o > 0; o >>= 1) acc += __shfl_xor(acc, o);
      if (lane == 0) u[k] = acc;
    } else if (widx == 1408) {
      float4 b0 = *(const float4*)(bh + c);
      float4 b1 = *(const float4*)(bh + c + 4);
      float4 b2 = *(const float4*)(bh + 512 + c);
      float4 b3 = *(const float4*)(bh + 512 + c + 4);
      float acc = b0.x * b2.x + b0.y * b2.y + b0.z * b2.z + b0.w * b2.w +
                  b1.x * b3.x + b1.y * b3.y + b1.z * b3.z + b1.w * b3.w;
#pragma unroll
      for (int o = 32; o > 0; o >>= 1) acc += __shfl_xor(acc, o);
      if (lane == 0) cbuf[0] = acc;
    } else if (widx < 1417) {
      int i = (widx - 1409) * 64 + lane;   // [0,512)
      bcat[i] = bh[1024 + i];
    }
  } else {
    // X -> fp16  +  lmr  (+ s0 zero)
    const int xb = b - 1028;             // [0,512)
    if (xb < 32) s0[xb * 256 + t] = 0.f;
    for (int i = t; i < 4608; i += 256) shmem[i] = Wg[i];
    __syncthreads();
    const int lane = t & 63, wid = t >> 6;
#pragma unroll
    for (int it = 0; it < 4; it++) {
      int pos = xb * 16 + it * 4 + wid;
      const float* x = X + (size_t)pos * 512 + lane * 8;
      float4 x0 = *(const float4*)x;
      float4 x1 = *(const float4*)(x + 4);
      float xs[8] = {x0.x, x0.y, x0.z, x0.w, x1.x, x1.y, x1.z, x1.w};
      ushort4 h0, h1;
      h0.x = f2h(xs[0]); h0.y = f2h(xs[1]); h0.z = f2h(xs[2]); h0.w = f2h(xs[3]);
      h1.x = f2h(xs[4]); h1.y = f2h(xs[5]); h1.z = f2h(xs[6]); h1.w = f2h(xs[7]);
      ((ushort4*)Xh)[pos * 128 + lane * 2] = h0;
      ((ushort4*)Xh)[pos * 128 + lane * 2 + 1] = h1;
      float p[9];
#pragma unroll
      for (int c = 0; c < 9; c++) p[c] = 0.f;
      const float* wrow = shmem + (lane * 8) * 9;
#pragma unroll
      for (int j = 0; j < 8; j++)
#pragma unroll
        for (int c = 0; c < 9; c++) p[c] += xs[j] * wrow[j * 9 + c];
#pragma unroll
      for (int c = 0; c < 9; c++)
#pragma unroll
        for (int o = 32; o > 0; o >>= 1) p[c] += __shfl_xor(p[c], o);
      if (lane == 0) {
#pragma unroll
        for (int c = 0; c < 9; c++) lmr[(size_t)pos * 9 + c] = p[c] + bg[c];
      }
    }
  }
#undef TI
}

// ---------------- unified fp16 MFMA GEMM ------------------------------------
// 128x128 tile, 4 waves (2x2), each 4x4 of 16x16x32 f16 MFMA, gl2lds staging.
// MODE 0 (gemmB, 64x15): y<4: s0[row] += sum_col (acc+u[col])*Xh[row,col]
//                        y>=4: HPb[row*1408 + (n0-512+..)] = f2h(acc + bcat[col])
// MODE 1 (gemmA, 11x4):  fp16 out Cb ld512; rows >=512 remapped +512 (Wcomb)
// MODE 2 (gemmC, 64x4):  out = sc4.x*hv + sc4.{y,z,w}.bv + acc
template <int MODE>
__global__ __launch_bounds__(256) void gemm_k(
    const u16* __restrict__ A, const u16* __restrict__ Bt,
    const float* __restrict__ ubias, const float* __restrict__ bcat,
    float* __restrict__ Cf, u16* __restrict__ Cb, int Kdim,
    const u16* __restrict__ Xh, float* __restrict__ s0,
    const float4* __restrict__ sc4, const u16* __restrict__ HPb,
    const float* __restrict__ bb, const float* __restrict__ bm,
    const float* __restrict__ be) {
  __shared__ __align__(16) u16 As[128 * 32];
  __shared__ __align__(16) u16 Bs[128 * 32];

  const int t = threadIdx.x;
  const int lane = t & 63;
  const int wid = t >> 6;
  const int m0 = blockIdx.x * 128;
  const int n0 = blockIdx.y * 128;
  const int wm = (wid & 1) * 64;
  const int wn = (wid >> 1) * 64;
  const int fr = lane & 15;
  const int kq = (lane >> 4) * 8;

  f32x4 acc[4][4];
#pragma unroll
  for (int i = 0; i < 4; i++)
#pragma unroll
    for (int j = 0; j < 4; j++) acc[i][j] = (f32x4){0.f, 0.f, 0.f, 0.f};

  for (int k0 = 0; k0 < Kdim; k0 += 32) {
    __syncthreads();
#pragma unroll
    for (int p = 0; p < 2; p++) {
      int li = p * 256 + t;
      int row = li >> 2;
      int so = (li & 3) * 8;
      gl2lds(&A[(size_t)(m0 + row) * Kdim + k0 + so], &As[li * 8]);
      gl2lds(&Bt[(size_t)(n0 + row) * Kdim + k0 + so], &Bs[li * 8]);
    }
    __syncthreads();
    f16x8 av[4], bv[4];
#pragma unroll
    for (int i = 0; i < 4; i++) {
      av[i] = *(const f16x8*)&As[(wm + i * 16 + fr) * 32 + kq];
      bv[i] = *(const f16x8*)&Bs[(wn + i * 16 + fr) * 32 + kq];
    }
#pragma unroll
    for (int mt = 0; mt < 4; mt++)
#pragma unroll
      for (int nt = 0; nt < 4; nt++)
        acc[mt][nt] = __builtin_amdgcn_mfma_f32_16x16x32_f16(
            av[mt], bv[nt], acc[mt][nt], 0, 0, 0);
  }

  const int r0 = (lane >> 4) * 4;
  if constexpr (MODE == 0) {
    if (blockIdx.y < 4) {
      float pl[4][4];
#pragma unroll
      for (int mt = 0; mt < 4; mt++)
#pragma unroll
        for (int r = 0; r < 4; r++) pl[mt][r] = 0.f;
#pragma unroll
      for (int mt = 0; mt < 4; mt++)
#pragma unroll
        for (int nt = 0; nt < 4; nt++) {
          int col = n0 + wn + nt * 16 + fr;
          float bv2 = ubias[col];
#pragma unroll
          for (int r = 0; r < 4; r++) {
            int row = m0 + wm + mt * 16 + r0 + r;
            pl[mt][r] += (acc[mt][nt][r] + bv2) * h2f(Xh[(size_t)row * 512 + col]);
          }
        }
#pragma unroll
      for (int mt = 0; mt < 4; mt++)
#pragma unroll
        for (int r = 0; r < 4; r++) {
          float p = pl[mt][r];
          p += __shfl_xor(p, 1);
          p += __shfl_xor(p, 2);
          p += __shfl_xor(p, 4);
          p += __shfl_xor(p, 8);
          if (fr == r) {
            int row = m0 + wm + mt * 16 + r0 + r;
            atomicAdd(&s0[row], p);
          }
        }
      return;
    }
#pragma unroll
    for (int mt = 0; mt < 4; mt++)
#pragma unroll
      for (int nt = 0; nt < 4; nt++) {
        int col = n0 - 512 + wn + nt * 16 + fr;
        float bv2 = bcat[col];
#pragma unroll
        for (int r = 0; r < 4; r++) {
          int row = m0 + wm + mt * 16 + r0 + r;
          Cb[(size_t)row * 1408 + col] = f2h(acc[mt][nt][r] + bv2);
        }
      }
  } else if constexpr (MODE == 1) {
#pragma unroll
    for (int mt = 0; mt < 4; mt++)
#pragma unroll
      for (int nt = 0; nt < 4; nt++) {
        int col = n0 + wn + nt * 16 + fr;
#pragma unroll
        for (int r = 0; r < 4; r++) {
          int row = m0 + wm + mt * 16 + r0 + r;
          int orow = row < 512 ? row : row + 512;   // Wcomb rows -> 1024..1919
          Cb[(size_t)orow * 512 + col] = f2h(acc[mt][nt][r]);
        }
      }
  } else {
#pragma unroll
    for (int mt = 0; mt < 4; mt++)
#pragma unroll
      for (int nt = 0; nt < 4; nt++) {
        int col = n0 + wn + nt * 16 + fr;
        float b0 = bb[512 + col];
        float b1 = bm[512 + col];
        float b2 = be[512 + col];
#pragma unroll
        for (int r = 0; r < 4; r++) {
          int row = m0 + wm + mt * 16 + r0 + r;
          float4 s = sc4[row];
          float hv = h2f(HPb[(size_t)row * 1408 + col]);
          Cf[(size_t)row * 512 + col] =
              s.x * hv + s.y * b0 + s.z * b1 + s.w * b2 + acc[mt][nt][r];
        }
      }
  }
}

// ---------------- fused gather / scores / softmax / aggregate ---------------
// Only invalid candidates (w >= len) survive the reference's mask (valid get
// -1e10 -> weight 0).  deg = mask!=0 && all 15 valid -> uniform 1/16 weights.
__global__ __launch_bounds__(256) void attn_kernel(
    const int* __restrict__ masks, const int* __restrict__ begins,
    const int* __restrict__ blens, const int* __restrict__ middles,
    const int* __restrict__ mlens, const int* __restrict__ ends,
    const int* __restrict__ elens, const float* __restrict__ emb,
    const u16* __restrict__ HPb, const float* __restrict__ lmr,
    const float* __restrict__ s0buf, const float* __restrict__ cbuf,
    float4* __restrict__ sc4, u16* __restrict__ Ebar) {
  const int t = threadIdx.x;
  const int lane = t & 63;
  const int wid = t >> 6;
  const int pos = blockIdx.x * 4 + wid;
  const int mask = masks[pos];
  u16* erow = Ebar + (size_t)pos * 768;

  int l0 = min(blens[pos], 5), l1 = min(mlens[pos], 5), l2 = min(elens[pos], 5);
  int nv = l0 + l1 + l2;

  if (mask == 0) {
    // gates 0 -> lattice values exactly 0; only hidden (score s0) vs the
    // ninv invalid candidates (score 0) matter.
    float s0 = s0buf[pos] + cbuf[0];
    int ninv = 15 - nv;
    float w0;
    if (ninv == 0) {
      w0 = 1.f;
    } else {
      float Mx = fmaxf(s0, 0.f);
      float e0 = __expf(s0 - Mx);
      w0 = e0 / (e0 + (float)ninv * __expf(-Mx));
    }
    if (lane == 0) sc4[pos] = make_float4(w0, 0.f, 0.f, 0.f);
    ushort4 zz; zz.x = zz.y = zz.z = zz.w = 0;
    *(ushort4*)(erow + 0 * 256 + lane * 4) = zz;
    *(ushort4*)(erow + 1 * 256 + lane * 4) = zz;
    *(ushort4*)(erow + 2 * 256 + lane * 4) = zz;
  } else {
    // inline gates from lmr
    const int s = pos & (SS - 1);
    float g[3];
    if (s == 0 || s == SS - 1) {
      g[0] = 1.f; g[1] = 0.f; g[2] = 1.f;
    } else {
      const float* p0 = lmr + (size_t)(pos - 1) * 9;
      const float* p1 = lmr + (size_t)pos * 9;
      const float* p2 = lmr + (size_t)(pos + 1) * 9;
      g[0] = sigm(p0[0] + p1[3] + p2[6]);
      g[1] = sigm(p0[1] + p1[4] + p2[7]);
      g[2] = sigm(p0[2] + p1[5] + p2[8]);
    }
    const bool deg = (nv == 15);
    int l[3] = {l0, l1, l2};
    if (deg) { l[0] = 0; l[1] = 0; l[2] = 0; }

    float4 Pt[3];
    float qb[3];
    if (!deg) {
      const u16* prow = HPb + (size_t)pos * 1408 + 512;
#pragma unroll
      for (int ty = 0; ty < 3; ty++) {
        ushort4 pu = *(const ushort4*)(prow + ty * 256 + lane * 4);
        Pt[ty].x = h2f(pu.x); Pt[ty].y = h2f(pu.y);
        Pt[ty].z = h2f(pu.z); Pt[ty].w = h2f(pu.w);
        qb[ty] = h2f(prow[768 + ty]);
      }
    }
    const int* idxp[3];
    idxp[0] = begins + (size_t)pos * 5;
    idxp[1] = middles + (size_t)pos * 5;
    idxp[2] = ends + (size_t)pos * 5;

    float4 ev[3][5];
    float scv[3][5];
    float Mx = deg ? 0.f : -3.0e38f;
#pragma unroll
    for (int ty = 0; ty < 3; ty++) {
#pragma unroll
      for (int w = 0; w < 5; w++) {
        bool act = (w >= l[ty]);      // wave-uniform
        if (act) {
          ev[ty][w] = *(const float4*)(emb + (size_t)idxp[ty][w] * 256 + lane * 4);
          float sv = 0.f;
          if (!deg) {
            float4 e = ev[ty][w];
            float d = Pt[ty].x * e.x + Pt[ty].y * e.y + Pt[ty].z * e.z + Pt[ty].w * e.w;
#pragma unroll
            for (int o = 32; o > 0; o >>= 1) d += __shfl_xor(d, o);
            sv = g[ty] * (d + qb[ty]);
          }
          scv[ty][w] = sv;
          Mx = fmaxf(Mx, sv);
        }
      }
    }
    float wts0 = deg ? 1.f : 0.f;     // hidden survives only in deg case
    float zs = wts0;
    float wts[3][5];
#pragma unroll
    for (int ty = 0; ty < 3; ty++)
#pragma unroll
      for (int w = 0; w < 5; w++) {
        bool act = (w >= l[ty]);
        float wv = act ? __expf(scv[ty][w] - Mx) : 0.f;
        wts[ty][w] = wv;
        zs += wv;
      }
    float inv = 1.f / zs;
    float alpha[3];
#pragma unroll
    for (int ty = 0; ty < 3; ty++) {
      float ax = 0.f, ay = 0.f, az = 0.f, aw = 0.f, asum = 0.f;
#pragma unroll
      for (int w = 0; w < 5; w++) {
        if (w >= l[ty]) {
          float wk = wts[ty][w];
          asum += wk;
          ax += wk * ev[ty][w].x;
          ay += wk * ev[ty][w].y;
          az += wk * ev[ty][w].z;
          aw += wk * ev[ty][w].w;
        }
      }
      float sg = g[ty] * inv;
      alpha[ty] = sg * asum;
      ushort4 h;
      h.x = f2h(ax * sg); h.y = f2h(ay * sg); h.z = f2h(az * sg); h.w = f2h(aw * sg);
      *(ushort4*)(erow + ty * 256 + lane * 4) = h;
    }
    if (lane == 0) sc4[pos] = make_float4(wts0 * inv, alpha[0], alpha[1], alpha[2]);
  }
}

// ---------------------------------------------------------------------------
extern "C" void kernel_launch(void* const* d_in, const int* in_sizes, int n_in,
                              void* d_out, int out_size, void* d_ws, size_t ws_size,
                              hipStream_t stream) {
  const float* hiddens = (const float*)d_in[0];
  const int* masks = (const int*)d_in[1];
  const int* begins = (const int*)d_in[2];
  const int* blens = (const int*)d_in[3];
  const int* middles = (const int*)d_in[4];
  const int* mlens = (const int*)d_in[5];
  const int* ends = (const int*)d_in[6];
  const int* elens = (const int*)d_in[7];
  const float* emb = (const float*)d_in[8];
  const float* Wh = (const float*)d_in[9];
  const float* bh = (const float*)d_in[10];
  const float* Wb = (const float*)d_in[11];
  const float* bb = (const float*)d_in[12];
  const float* Wm = (const float*)d_in[13];
  const float* bm = (const float*)d_in[14];
  const float* We = (const float*)d_in[15];
  const float* be = (const float*)d_in[16];
  const float* Wg = (const float*)d_in[17];
  const float* bg = (const float*)d_in[18];
  float* out = (float*)d_out;

  char* ws = (char*)d_ws;
  size_t off = 0;
  auto alloc = [&](size_t bytes) -> char* {
    char* p = ws + off;
    off += (bytes + 255) & ~(size_t)255;
    return p;
  };
  u16* Xh = (u16*)alloc((size_t)8192 * 512 * 2);
  u16* Whq = (u16*)alloc((size_t)512 * 512 * 2);
  u16* Acat = (u16*)alloc((size_t)1408 * 512 * 2);   // [Whk | WkT]
  u16* Breg = (u16*)alloc((size_t)1920 * 512 * 2);   // [M | WhvT | Wcomb]
  u16* WvT = (u16*)alloc((size_t)512 * 768 * 2);
  u16* HPb = (u16*)alloc((size_t)8192 * 1408 * 2);   // [hv fp16 | P fp16]
  float* lmr = (float*)alloc((size_t)8192 * 9 * 4);
  float* s0 = (float*)alloc((size_t)8192 * 4);
  float* bcat = (float*)alloc((size_t)1408 * 4);
  float* u = (float*)alloc((size_t)512 * 4);
  float* cbuf = (float*)alloc((size_t)4);
  float* sc4 = (float*)alloc((size_t)8192 * 4 * 4);
  u16* Ebar = (u16*)alloc((size_t)8192 * 768 * 2);
  if (off > ws_size) return;  // fail loudly (output stays poisoned)

  // 1) all preps in one launch
  prep_all<<<1540, 256, 0, stream>>>(hiddens, Wg, bg, Wh, Wb, Wm, We, bb, bm, be,
                                     bh, Xh, lmr, s0, Breg, Acat, Whq, WvT,
                                     bcat, u, cbuf);
  // 2) gemmA: Breg[M rows 0..511; Wcomb rows 1024..1919] = Acat @ Whq^T
  gemm_k<1><<<dim3(11, 4), 256, 0, stream>>>(
      Acat, Whq, nullptr, nullptr, nullptr, Breg, 512, nullptr, nullptr,
      nullptr, nullptr, nullptr, nullptr, nullptr);
  // 3) gemmB: y<4 -> s0; y>=4 -> HPb = Xh @ [WhvT|Wcomb]^T + bcat
  gemm_k<0><<<dim3(64, 15), 256, 0, stream>>>(
      Xh, Breg, u, bcat, nullptr, HPb, 512, Xh, s0,
      nullptr, nullptr, nullptr, nullptr, nullptr);
  // 4) fused attention -> sc4 + Ebar
  attn_kernel<<<2048, 256, 0, stream>>>(masks, begins, blens, middles, mlens,
                                        ends, elens, emb, HPb, lmr, s0, cbuf,
                                        (float4*)sc4, Ebar);
  // 5) gemmC: out = sc4 epilogue + Ebar @ WvT^T
  gemm_k<2><<<dim3(64, 4), 256, 0, stream>>>(
      Ebar, WvT, nullptr, nullptr, out, nullptr, 768, nullptr, nullptr,
      (const float4*)sc4, HPb, bb, bm, be);
}

// Round 6
// 282.262 us; speedup vs baseline: 1.4334x; 1.0202x over previous
//
#include <hip/hip_runtime.h>
#include <cstdint>
#include <cstddef>

// ---------------------------------------------------------------------------
// GatedLatticeLayer on MI355X.  B=16 S=512 W=5 H=512 E=256 V=100000.
// MROWS = B*S = 8192.
//
// Round 6 (5 launches + 8B memset), all-fp16 MFMA:
//   prep_all: X->fp16, lmr, weight transposes/copies, bias dots, mask PARTITION
//             (group0 = mask==0 slots [0,cnt0) ascending; group1 descending
//              from 8191; idx: slot->pos, perm: pos->slot; bijection => every
//              entry written, no poison reads)
//   gemmA:    Breg[M | (WhvT) | Wcomb] = Acat @ Whq^T     (fp16)
//   gemmB:    y<4:  s0c[slot] += rowdot(Xh[idx]@M^T + u, Xh[idx])  (group0 only)
//             y4-7: HPb hv cols (all rows, pos space)
//             y8+:  HPb P cols  (group1 slots only, row-remapped via idx)
//             blocks outside their group's slot range early-exit.
//   attn:     slot=perm[pos]; only INVALID candidates (w>=len) survive the
//             reference mask; deg (all 15 valid, mask!=0) -> uniform 1/16.
//   gemmC:    out = w0*hv + sum_t a_t*bv_t + Ebar @ WvT^T
// GEMMs use BK=64 as two sequential BK=32 panels (m97-identical LDS banks,
// half the barriers).
// ---------------------------------------------------------------------------

typedef unsigned short u16;
typedef _Float16 f16;
typedef __attribute__((ext_vector_type(8))) f16 f16x8;
typedef __attribute__((ext_vector_type(4))) float f32x4;

#define MROWS 8192
#define SS 512

static __device__ __forceinline__ u16 f2h(float x) {
  f16 h = (f16)x;
  return __builtin_bit_cast(u16, h);
}
static __device__ __forceinline__ float h2f(u16 h) {
  return (float)__builtin_bit_cast(f16, h);
}
static __device__ __forceinline__ float sigm(float x) { return 1.f / (1.f + __expf(-x)); }

static __device__ __forceinline__ void gl2lds(const u16* g, u16* l) {
  __builtin_amdgcn_global_load_lds(
      (const __attribute__((address_space(1))) unsigned int*)g,
      (__attribute__((address_space(3))) unsigned int*)l, 16, 0, 0);
}

// ---------------- merged prep: weights + dots + X/lmr + partition -----------
// [0,64):      WhvT -> Breg rows 512..1023 (fp16)
// [64,128):    Whq (fp16) + Whk -> Acat rows 0..511
// [128,576):   WkT -> Acat rows 512..1407
// [576,672):   WvT (512x768 fp16)
// [672,1028):  wave dots: bcat[512+n]=bcomb, u, cb, bcat[0:512) copy
// [1028,1540): X -> fp16 + lmr (+ s0 zero)
// [1540,1572): mask partition -> idx/perm (cnts pre-zeroed via memsetAsync)
__global__ __launch_bounds__(256) void prep_all(
    const float* __restrict__ X, const float* __restrict__ Wg,
    const float* __restrict__ bg, const float* __restrict__ Wh,
    const float* __restrict__ Wb, const float* __restrict__ Wm,
    const float* __restrict__ We, const float* __restrict__ bb,
    const float* __restrict__ bm, const float* __restrict__ be,
    const float* __restrict__ bh, const int* __restrict__ masks,
    u16* __restrict__ Xh, float* __restrict__ lmr, float* __restrict__ s0,
    u16* __restrict__ Breg, u16* __restrict__ Acat, u16* __restrict__ Whq,
    u16* __restrict__ WvT, float* __restrict__ bcat, float* __restrict__ u,
    float* __restrict__ cbuf, int* __restrict__ idx, int* __restrict__ perm,
    int* __restrict__ cnts) {
  __shared__ float shmem[4608];            // tile (64x65=4160) or wg (4608)
#define TI(r, c) shmem[(r)*65 + (c)]
  const int b = blockIdx.x;
  const int t = threadIdx.x;
  if (b < 64) {
    int k0 = (b & 7) * 64;
    int n0 = (b >> 3) * 64;
#pragma unroll
    for (int i = 0; i < 16; i++) {
      int li = i * 256 + t; int r = li >> 6, c = li & 63;
      TI(r, c) = Wh[(size_t)(k0 + r) * 1536 + 1024 + n0 + c];
    }
    __syncthreads();
#pragma unroll
    for (int i = 0; i < 16; i++) {
      int li = i * 256 + t; int r = li >> 6, c = li & 63;
      Breg[(size_t)(512 + n0 + r) * 512 + k0 + c] = f2h(TI(c, r));
    }
  } else if (b < 128) {
#pragma unroll
    for (int i = 0; i < 4; i++) {
      int q4 = (b - 64) * 1024 + t * 4 + i;   // [0, 65536) float4 index
      int k = q4 >> 7;
      int c4 = (q4 & 127) * 4;
      float4 vq = *(const float4*)(Wh + (size_t)k * 1536 + c4);
      float4 vk = *(const float4*)(Wh + (size_t)k * 1536 + 512 + c4);
      ushort4 qh, kh;
      qh.x = f2h(vq.x); qh.y = f2h(vq.y); qh.z = f2h(vq.z); qh.w = f2h(vq.w);
      kh.x = f2h(vk.x); kh.y = f2h(vk.y); kh.z = f2h(vk.z); kh.w = f2h(vk.w);
      size_t o = (size_t)k * 512 + c4;
      *(ushort4*)(Whq + o) = qh;
      *(ushort4*)(Acat + o) = kh;
    }
  } else if (b < 576) {
    int tid = (b - 128) * 256 + t;      // [0, 896*128)
    int n = tid >> 7;
    int kq = (tid & 127) * 4;
    float4 v;
    if (n < 768) {
      int ty = n >> 8, c = n & 255;
      const float* src = (ty == 0 ? Wb : ty == 1 ? Wm : We) + (size_t)c * 1024 + kq;
      v = *(const float4*)src;
    } else if (n < 771) {
      int ty = n - 768;
      const float* src = (ty == 0 ? bb : ty == 1 ? bm : be) + kq;
      v = *(const float4*)src;
    } else {
      v = make_float4(0.f, 0.f, 0.f, 0.f);
    }
    ushort4 h; h.x = f2h(v.x); h.y = f2h(v.y); h.z = f2h(v.z); h.w = f2h(v.w);
    ((ushort4*)(Acat + (size_t)512 * 512))[tid] = h;
  } else if (b < 672) {
    int idx2 = b - 576;                 // [0,96)
    int ty = idx2 >> 5;
    int rem = idx2 & 31;
    int c0 = (rem & 3) * 64;
    int n0 = (rem >> 2) * 64;
    const float* Wsrc = ty == 0 ? Wb : ty == 1 ? Wm : We;
#pragma unroll
    for (int i = 0; i < 16; i++) {
      int li = i * 256 + t; int r = li >> 6, c = li & 63;
      TI(r, c) = Wsrc[(size_t)(c0 + r) * 1024 + 512 + n0 + c];
    }
    __syncthreads();
#pragma unroll
    for (int i = 0; i < 16; i++) {
      int li = i * 256 + t; int r = li >> 6, c = li & 63;
      WvT[(size_t)(n0 + r) * 768 + ty * 256 + c0 + c] = f2h(TI(c, r));
    }
  } else if (b < 1028) {
    // wave-parallel dots: one wave per output scalar.
    const int lane = t & 63;
    const int widx = (b - 672) * 4 + (t >> 6);   // [0,1424)
    const int c = lane * 8;
    if (widx < 896) {
      int n = widx;
      float acc = 0.f;
      if (n < 771) {
        const float* src;
        if (n < 768) {
          int ty = n >> 8, ce = n & 255;
          src = (ty == 0 ? Wb : ty == 1 ? Wm : We) + (size_t)ce * 1024 + c;
        } else {
          int ty = n - 768;
          src = (ty == 0 ? bb : ty == 1 ? bm : be) + c;
        }
        float4 a0 = *(const float4*)src;
        float4 a1 = *(const float4*)(src + 4);
        float4 b0 = *(const float4*)(bh + c);
        float4 b1 = *(const float4*)(bh + c + 4);
        acc = a0.x * b0.x + a0.y * b0.y + a0.z * b0.z + a0.w * b0.w +
              a1.x * b1.x + a1.y * b1.y + a1.z * b1.z + a1.w * b1.w;
      }
#pragma unroll
      for (int o = 32; o > 0; o >>= 1) acc += __shfl_xor(acc, o);
      if (lane == 0) bcat[512 + n] = acc;
    } else if (widx < 1408) {
      int k = widx - 896;
      const float* wr = Wh + (size_t)k * 1536;
      float4 a0 = *(const float4*)(wr + c);
      float4 a1 = *(const float4*)(wr + c + 4);
      float4 a2 = *(const float4*)(wr + 512 + c);
      float4 a3 = *(const float4*)(wr + 512 + c + 4);
      float4 b0 = *(const float4*)(bh + 512 + c);
      float4 b1 = *(const float4*)(bh + 512 + c + 4);
      float4 b2 = *(const float4*)(bh + c);
      float4 b3 = *(const float4*)(bh + c + 4);
      float acc = a0.x * b0.x + a0.y * b0.y + a0.z * b0.z + a0.w * b0.w +
                  a1.x * b1.x + a1.y * b1.y + a1.z * b1.z + a1.w * b1.w +
                  a2.x * b2.x + a2.y * b2.y + a2.z * b2.z + a2.w * b2.w +
                  a3.x * b3.x + a3.y * b3.y + a3.z * b3.z + a3.w * b3.w;
#pragma unroll
      for (int o = 32; o > 0; o >>= 1) acc += __shfl_xor(acc, o);
      if (lane == 0) u[k] = acc;
    } else if (widx == 1408) {
      float4 b0 = *(const float4*)(bh + c);
      float4 b1 = *(const float4*)(bh + c + 4);
      float4 b2 = *(const float4*)(bh + 512 + c);
      float4 b3 = *(const float4*)(bh + 512 + c + 4);
      float acc = b0.x * b2.x + b0.y * b2.y + b0.z * b2.z + b0.w * b2.w +
                  b1.x * b3.x + b1.y * b3.y + b1.z * b3.z + b1.w * b3.w;
#pragma unroll
      for (int o = 32; o > 0; o >>= 1) acc += __shfl_xor(acc, o);
      if (lane == 0) cbuf[0] = acc;
    } else if (widx < 1417) {
      int i = (widx - 1409) * 64 + lane;   // [0,512)
      bcat[i] = bh[1024 + i];
    }
  } else if (b < 1540) {
    // X -> fp16  +  lmr  (+ s0 zero)
    const int xb = b - 1028;             // [0,512)
    if (xb < 32) s0[xb * 256 + t] = 0.f;
    for (int i = t; i < 4608; i += 256) shmem[i] = Wg[i];
    __syncthreads();
    const int lane = t & 63, wid = t >> 6;
#pragma unroll
    for (int it = 0; it < 4; it++) {
      int pos = xb * 16 + it * 4 + wid;
      const float* x = X + (size_t)pos * 512 + lane * 8;
      float4 x0 = *(const float4*)x;
      float4 x1 = *(const float4*)(x + 4);
      float xs[8] = {x0.x, x0.y, x0.z, x0.w, x1.x, x1.y, x1.z, x1.w};
      ushort4 h0, h1;
      h0.x = f2h(xs[0]); h0.y = f2h(xs[1]); h0.z = f2h(xs[2]); h0.w = f2h(xs[3]);
      h1.x = f2h(xs[4]); h1.y = f2h(xs[5]); h1.z = f2h(xs[6]); h1.w = f2h(xs[7]);
      ((ushort4*)Xh)[pos * 128 + lane * 2] = h0;
      ((ushort4*)Xh)[pos * 128 + lane * 2 + 1] = h1;
      float p[9];
#pragma unroll
      for (int c = 0; c < 9; c++) p[c] = 0.f;
      const float* wrow = shmem + (lane * 8) * 9;
#pragma unroll
      for (int j = 0; j < 8; j++)
#pragma unroll
        for (int c = 0; c < 9; c++) p[c] += xs[j] * wrow[j * 9 + c];
#pragma unroll
      for (int c = 0; c < 9; c++)
#pragma unroll
        for (int o = 32; o > 0; o >>= 1) p[c] += __shfl_xor(p[c], o);
      if (lane == 0) {
#pragma unroll
        for (int c = 0; c < 9; c++) lmr[(size_t)pos * 9 + c] = p[c] + bg[c];
      }
    }
  } else {
    // mask partition (cnts[0..1] pre-zeroed on stream)
    const int lane = t & 63;
    const int pos = (b - 1540) * 256 + t;
    bool is0 = masks[pos] == 0;
    unsigned long long bal = __ballot(is0);
    unsigned long long below = (lane == 0) ? 0ull : (~0ull >> (64 - lane));
    int rank0 = __popcll(bal & below);
    int rank1 = __popcll((~bal) & below);
    int n0w = __popcll(bal);
    int base0 = 0, base1 = 0;
    if (lane == 0) {
      base0 = atomicAdd(&cnts[0], n0w);
      base1 = atomicAdd(&cnts[1], 64 - n0w);
    }
    base0 = __shfl(base0, 0);
    base1 = __shfl(base1, 0);
    int slot = is0 ? (base0 + rank0) : (8191 - (base1 + rank1));
    perm[pos] = slot;
    idx[slot] = pos;
  }
#undef TI
}

// ---------------- unified fp16 MFMA GEMM (BK=64 as 2x BK=32 panels) ---------
// 128x128 tile, 4 waves (2x2), each 4x4 of 16x16x32 f16 MFMA, gl2lds staging.
// MODE 0 (gemmB, 64x15):
//   y<4:  group0 slots; A rows = Xh[idx[slot]]; s0c[slot] += rowdot(.+u, Xh)
//   y4-7: all rows pos space; HPb[row*1408 + col] = f2h(acc + bcat[col])
//   y>=8: group1 slots; A rows = Xh[idx[slot]]; HPb[slot*1408+512+pcol]
// MODE 1 (gemmA, 11x4):  fp16 out ld512; rows >=512 remapped +512 (Wcomb)
// MODE 2 (gemmC, 64x4):  out = sc4.x*hv + sc4.{y,z,w}.bv + acc
template <int MODE>
__global__ __launch_bounds__(256) void gemm_k(
    const u16* __restrict__ A, const u16* __restrict__ Bt,
    const float* __restrict__ ubias, const float* __restrict__ bcat,
    float* __restrict__ Cf, u16* __restrict__ Cb, int Kdim,
    const u16* __restrict__ Xh, float* __restrict__ s0c,
    const int* __restrict__ idx, const int* __restrict__ cnts,
    const float4* __restrict__ sc4, const u16* __restrict__ HPb,
    const float* __restrict__ bb, const float* __restrict__ bm,
    const float* __restrict__ be) {
  __shared__ __align__(16) u16 As[2 * 128 * 32];
  __shared__ __align__(16) u16 Bs[2 * 128 * 32];

  const int t = threadIdx.x;
  const int lane = t & 63;
  const int wid = t >> 6;
  const int m0 = blockIdx.x * 128;
  const int n0 = blockIdx.y * 128;

  bool remap = false;
  if constexpr (MODE == 0) {
    const int cnt0 = cnts[0];
    if (blockIdx.y < 4) {
      if (m0 >= cnt0) return;          // group0 only
      remap = true;
    } else if (blockIdx.y >= 8) {
      if (m0 + 128 <= cnt0) return;    // group1 only
      remap = true;
    }
  }

  // two A rows + two B rows staged per thread (rows r, r+64), koff chunk
  int ra0 = m0 + (t >> 2), ra1 = m0 + 64 + (t >> 2);
  if (MODE == 0 && remap) { ra0 = idx[ra0]; ra1 = idx[ra1]; }
  const int rb0 = n0 + (t >> 2), rb1 = n0 + 64 + (t >> 2);
  const int koff = (t & 3) * 8;
  const int lds0 = (t >> 2) * 32 + koff;       // rows 0..63 panel slot
  const int lds1 = 2048 + lds0;                // rows 64..127

  const int wm = (wid & 1) * 64;
  const int wn = (wid >> 1) * 64;
  const int fr = lane & 15;
  const int kq = (lane >> 4) * 8;

  f32x4 acc[4][4];
#pragma unroll
  for (int i = 0; i < 4; i++)
#pragma unroll
    for (int j = 0; j < 4; j++) acc[i][j] = (f32x4){0.f, 0.f, 0.f, 0.f};

  for (int k0 = 0; k0 < Kdim; k0 += 64) {
    __syncthreads();
#pragma unroll
    for (int pn = 0; pn < 2; pn++) {
      const int kb = k0 + pn * 32 + koff;
      gl2lds(&A[(size_t)ra0 * Kdim + kb], &As[pn * 4096 + lds0]);
      gl2lds(&A[(size_t)ra1 * Kdim + kb], &As[pn * 4096 + lds1]);
      gl2lds(&Bt[(size_t)rb0 * Kdim + kb], &Bs[pn * 4096 + lds0]);
      gl2lds(&Bt[(size_t)rb1 * Kdim + kb], &Bs[pn * 4096 + lds1]);
    }
    __syncthreads();
#pragma unroll
    for (int pn = 0; pn < 2; pn++) {
      f16x8 av[4], bv[4];
#pragma unroll
      for (int i = 0; i < 4; i++) {
        av[i] = *(const f16x8*)&As[pn * 4096 + (wm + i * 16 + fr) * 32 + kq];
        bv[i] = *(const f16x8*)&Bs[pn * 4096 + (wn + i * 16 + fr) * 32 + kq];
      }
#pragma unroll
      for (int mt = 0; mt < 4; mt++)
#pragma unroll
        for (int nt = 0; nt < 4; nt++)
          acc[mt][nt] = __builtin_amdgcn_mfma_f32_16x16x32_f16(
              av[mt], bv[nt], acc[mt][nt], 0, 0, 0);
    }
  }

  const int r0 = (lane >> 4) * 4;
  if constexpr (MODE == 0) {
    if (blockIdx.y < 4) {
      float pl[4][4];
      int xrow[4][4];
#pragma unroll
      for (int mt = 0; mt < 4; mt++)
#pragma unroll
        for (int r = 0; r < 4; r++) {
          pl[mt][r] = 0.f;
          xrow[mt][r] = idx[m0 + wm + mt * 16 + r0 + r];
        }
#pragma unroll
      for (int mt = 0; mt < 4; mt++)
#pragma unroll
        for (int nt = 0; nt < 4; nt++) {
          int col = n0 + wn + nt * 16 + fr;
          float bv2 = ubias[col];
#pragma unroll
          for (int r = 0; r < 4; r++)
            pl[mt][r] += (acc[mt][nt][r] + bv2) *
                         h2f(Xh[(size_t)xrow[mt][r] * 512 + col]);
        }
#pragma unroll
      for (int mt = 0; mt < 4; mt++)
#pragma unroll
        for (int r = 0; r < 4; r++) {
          float p = pl[mt][r];
          p += __shfl_xor(p, 1);
          p += __shfl_xor(p, 2);
          p += __shfl_xor(p, 4);
          p += __shfl_xor(p, 8);
          if (fr == r) {
            int slot = m0 + wm + mt * 16 + r0 + r;
            atomicAdd(&s0c[slot], p);
          }
        }
      return;
    }
    if (blockIdx.y < 8) {
#pragma unroll
      for (int mt = 0; mt < 4; mt++)
#pragma unroll
        for (int nt = 0; nt < 4; nt++) {
          int col = n0 - 512 + wn + nt * 16 + fr;
          float bv2 = bcat[col];
#pragma unroll
          for (int r = 0; r < 4; r++) {
            int row = m0 + wm + mt * 16 + r0 + r;
            Cb[(size_t)row * 1408 + col] = f2h(acc[mt][nt][r] + bv2);
          }
        }
    } else {
#pragma unroll
      for (int mt = 0; mt < 4; mt++)
#pragma unroll
        for (int nt = 0; nt < 4; nt++) {
          int pcol = n0 - 1024 + wn + nt * 16 + fr;
          float bv2 = bcat[512 + pcol];
#pragma unroll
          for (int r = 0; r < 4; r++) {
            int slot = m0 + wm + mt * 16 + r0 + r;
            Cb[(size_t)slot * 1408 + 512 + pcol] = f2h(acc[mt][nt][r] + bv2);
          }
        }
    }
  } else if constexpr (MODE == 1) {
#pragma unroll
    for (int mt = 0; mt < 4; mt++)
#pragma unroll
      for (int nt = 0; nt < 4; nt++) {
        int col = n0 + wn + nt * 16 + fr;
#pragma unroll
        for (int r = 0; r < 4; r++) {
          int row = m0 + wm + mt * 16 + r0 + r;
          int orow = row < 512 ? row : row + 512;   // Wcomb rows -> 1024..1919
          Cb[(size_t)orow * 512 + col] = f2h(acc[mt][nt][r]);
        }
      }
  } else {
#pragma unroll
    for (int mt = 0; mt < 4; mt++)
#pragma unroll
      for (int nt = 0; nt < 4; nt++) {
        int col = n0 + wn + nt * 16 + fr;
        float b0 = bb[512 + col];
        float b1 = bm[512 + col];
        float b2 = be[512 + col];
#pragma unroll
        for (int r = 0; r < 4; r++) {
          int row = m0 + wm + mt * 16 + r0 + r;
          float4 s = sc4[row];
          float hv = h2f(HPb[(size_t)row * 1408 + col]);
          Cf[(size_t)row * 512 + col] =
              s.x * hv + s.y * b0 + s.z * b1 + s.w * b2 + acc[mt][nt][r];
        }
      }
  }
}

// ---------------- fused gather / scores / softmax / aggregate ---------------
__global__ __launch_bounds__(256) void attn_kernel(
    const int* __restrict__ masks, const int* __restrict__ begins,
    const int* __restrict__ blens, const int* __restrict__ middles,
    const int* __restrict__ mlens, const int* __restrict__ ends,
    const int* __restrict__ elens, const float* __restrict__ emb,
    const u16* __restrict__ HPb, const float* __restrict__ lmr,
    const float* __restrict__ s0buf, const float* __restrict__ cbuf,
    const int* __restrict__ perm, float4* __restrict__ sc4,
    u16* __restrict__ Ebar) {
  const int t = threadIdx.x;
  const int lane = t & 63;
  const int wid = t >> 6;
  const int pos = blockIdx.x * 4 + wid;
  const int mask = masks[pos];
  const int slot = perm[pos];
  u16* erow = Ebar + (size_t)pos * 768;

  int l0 = min(blens[pos], 5), l1 = min(mlens[pos], 5), l2 = min(elens[pos], 5);
  int nv = l0 + l1 + l2;

  if (mask == 0) {
    float s0 = s0buf[slot] + cbuf[0];
    int ninv = 15 - nv;
    float w0;
    if (ninv == 0) {
      w0 = 1.f;
    } else {
      float Mx = fmaxf(s0, 0.f);
      float e0 = __expf(s0 - Mx);
      w0 = e0 / (e0 + (float)ninv * __expf(-Mx));
    }
    if (lane == 0) sc4[pos] = make_float4(w0, 0.f, 0.f, 0.f);
    ushort4 zz; zz.x = zz.y = zz.z = zz.w = 0;
    *(ushort4*)(erow + 0 * 256 + lane * 4) = zz;
    *(ushort4*)(erow + 1 * 256 + lane * 4) = zz;
    *(ushort4*)(erow + 2 * 256 + lane * 4) = zz;
  } else {
    const int s = pos & (SS - 1);
    float g[3];
    if (s == 0 || s == SS - 1) {
      g[0] = 1.f; g[1] = 0.f; g[2] = 1.f;
    } else {
      const float* p0 = lmr + (size_t)(pos - 1) * 9;
      const float* p1 = lmr + (size_t)pos * 9;
      const float* p2 = lmr + (size_t)(pos + 1) * 9;
      g[0] = sigm(p0[0] + p1[3] + p2[6]);
      g[1] = sigm(p0[1] + p1[4] + p2[7]);
      g[2] = sigm(p0[2] + p1[5] + p2[8]);
    }
    const bool deg = (nv == 15);
    int l[3] = {l0, l1, l2};
    if (deg) { l[0] = 0; l[1] = 0; l[2] = 0; }

    float4 Pt[3];
    float qb[3];
    if (!deg) {
      const u16* prow = HPb + (size_t)slot * 1408 + 512;
#pragma unroll
      for (int ty = 0; ty < 3; ty++) {
        ushort4 pu = *(const ushort4*)(prow + ty * 256 + lane * 4);
        Pt[ty].x = h2f(pu.x); Pt[ty].y = h2f(pu.y);
        Pt[ty].z = h2f(pu.z); Pt[ty].w = h2f(pu.w);
        qb[ty] = h2f(prow[768 + ty]);
      }
    }
    const int* idxp[3];
    idxp[0] = begins + (size_t)pos * 5;
    idxp[1] = middles + (size_t)pos * 5;
    idxp[2] = ends + (size_t)pos * 5;

    float4 ev[3][5];
    float scv[3][5];
    float Mx = deg ? 0.f : -3.0e38f;
#pragma unroll
    for (int ty = 0; ty < 3; ty++) {
#pragma unroll
      for (int w = 0; w < 5; w++) {
        bool act = (w >= l[ty]);      // wave-uniform
        if (act) {
          ev[ty][w] = *(const float4*)(emb + (size_t)idxp[ty][w] * 256 + lane * 4);
          float sv = 0.f;
          if (!deg) {
            float4 e = ev[ty][w];
            float d = Pt[ty].x * e.x + Pt[ty].y * e.y + Pt[ty].z * e.z + Pt[ty].w * e.w;
#pragma unroll
            for (int o = 32; o > 0; o >>= 1) d += __shfl_xor(d, o);
            sv = g[ty] * (d + qb[ty]);
          }
          scv[ty][w] = sv;
          Mx = fmaxf(Mx, sv);
        }
      }
    }
    float wts0 = deg ? 1.f : 0.f;     // hidden survives only in deg case
    float zs = wts0;
    float wts[3][5];
#pragma unroll
    for (int ty = 0; ty < 3; ty++)
#pragma unroll
      for (int w = 0; w < 5; w++) {
        bool act = (w >= l[ty]);
        float wv = act ? __expf(scv[ty][w] - Mx) : 0.f;
        wts[ty][w] = wv;
        zs += wv;
      }
    float inv = 1.f / zs;
    float alpha[3];
#pragma unroll
    for (int ty = 0; ty < 3; ty++) {
      float ax = 0.f, ay = 0.f, az = 0.f, aw = 0.f, asum = 0.f;
#pragma unroll
      for (int w = 0; w < 5; w++) {
        if (w >= l[ty]) {
          float wk = wts[ty][w];
          asum += wk;
          ax += wk * ev[ty][w].x;
          ay += wk * ev[ty][w].y;
          az += wk * ev[ty][w].z;
          aw += wk * ev[ty][w].w;
        }
      }
      float sg = g[ty] * inv;
      alpha[ty] = sg * asum;
      ushort4 h;
      h.x = f2h(ax * sg); h.y = f2h(ay * sg); h.z = f2h(az * sg); h.w = f2h(aw * sg);
      *(ushort4*)(erow + ty * 256 + lane * 4) = h;
    }
    if (lane == 0) sc4[pos] = make_float4(wts0 * inv, alpha[0], alpha[1], alpha[2]);
  }
}

// ---------------------------------------------------------------------------
extern "C" void kernel_launch(void* const* d_in, const int* in_sizes, int n_in,
                              void* d_out, int out_size, void* d_ws, size_t ws_size,
                              hipStream_t stream) {
  const float* hiddens = (const float*)d_in[0];
  const int* masks = (const int*)d_in[1];
  const int* begins = (const int*)d_in[2];
  const int* blens = (const int*)d_in[3];
  const int* middles = (const int*)d_in[4];
  const int* mlens = (const int*)d_in[5];
  const int* ends = (const int*)d_in[6];
  const int* elens = (const int*)d_in[7];
  const float* emb = (const float*)d_in[8];
  const float* Wh = (const float*)d_in[9];
  const float* bh = (const float*)d_in[10];
  const float* Wb = (const float*)d_in[11];
  const float* bb = (const float*)d_in[12];
  const float* Wm = (const float*)d_in[13];
  const float* bm = (const float*)d_in[14];
  const float* We = (const float*)d_in[15];
  const float* be = (const float*)d_in[16];
  const float* Wg = (const float*)d_in[17];
  const float* bg = (const float*)d_in[18];
  float* out = (float*)d_out;

  char* ws = (char*)d_ws;
  size_t off = 0;
  auto alloc = [&](size_t bytes) -> char* {
    char* p = ws + off;
    off += (bytes + 255) & ~(size_t)255;
    return p;
  };
  u16* Xh = (u16*)alloc((size_t)8192 * 512 * 2);
  u16* Whq = (u16*)alloc((size_t)512 * 512 * 2);
  u16* Acat = (u16*)alloc((size_t)1408 * 512 * 2);   // [Whk | WkT]
  u16* Breg = (u16*)alloc((size_t)1920 * 512 * 2);   // [M | WhvT | Wcomb]
  u16* WvT = (u16*)alloc((size_t)512 * 768 * 2);
  u16* HPb = (u16*)alloc((size_t)8192 * 1408 * 2);   // [hv fp16 | P fp16]
  float* lmr = (float*)alloc((size_t)8192 * 9 * 4);
  float* s0c = (float*)alloc((size_t)8192 * 4);
  float* bcat = (float*)alloc((size_t)1408 * 4);
  float* u = (float*)alloc((size_t)512 * 4);
  float* cbuf = (float*)alloc((size_t)4);
  float* sc4 = (float*)alloc((size_t)8192 * 4 * 4);
  u16* Ebar = (u16*)alloc((size_t)8192 * 768 * 2);
  int* idx = (int*)alloc((size_t)8192 * 4);
  int* perm = (int*)alloc((size_t)8192 * 4);
  int* cnts = (int*)alloc((size_t)256);
  if (off > ws_size) return;  // fail loudly (output stays poisoned)

  // 0) zero partition counters
  hipMemsetAsync(cnts, 0, 8, stream);
  // 1) all preps in one launch (incl. mask partition)
  prep_all<<<1572, 256, 0, stream>>>(hiddens, Wg, bg, Wh, Wb, Wm, We, bb, bm, be,
                                     bh, masks, Xh, lmr, s0c, Breg, Acat, Whq,
                                     WvT, bcat, u, cbuf, idx, perm, cnts);
  // 2) gemmA: Breg[M rows 0..511; Wcomb rows 1024..1919] = Acat @ Whq^T
  gemm_k<1><<<dim3(11, 4), 256, 0, stream>>>(
      Acat, Whq, nullptr, nullptr, nullptr, Breg, 512, nullptr, nullptr,
      nullptr, nullptr, nullptr, nullptr, nullptr, nullptr, nullptr);
  // 3) gemmB: y<4 -> s0 (group0); y4-7 -> hv (all); y>=8 -> P (group1)
  gemm_k<0><<<dim3(64, 15), 256, 0, stream>>>(
      Xh, Breg, u, bcat, nullptr, HPb, 512, Xh, s0c, idx, cnts,
      nullptr, nullptr, nullptr, nullptr, nullptr);
  // 4) fused attention -> sc4 + Ebar
  attn_kernel<<<2048, 256, 0, stream>>>(masks, begins, blens, middles, mlens,
                                        ends, elens, emb, HPb, lmr, s0c, cbuf,
                                        perm, (float4*)sc4, Ebar);
  // 5) gemmC: out = sc4 epilogue + Ebar @ WvT^T
  gemm_k<2><<<dim3(64, 4), 256, 0, stream>>>(
      Ebar, WvT, nullptr, nullptr, out, nullptr, 768, nullptr, nullptr,
      nullptr, nullptr, (const float4*)sc4, HPb, bb, bm, be);
}